// Round 1
// baseline (31638.281 us; speedup 1.0000x reference)
//
#include <hip/hip_runtime.h>

// Problem constants (from reference)
#define BB   2
#define LL   2048
#define DD   256
#define NH   8
#define DHH  32
#define MM   (BB*LL)        // 4096 rows per feature map
#define NLAYERS 8

// ---------------------------------------------------------------------------
// GEMM: Out[m,n] = (RES ? Res[m,n] : 0) + sum_k X[m,k] * W[n,k]
// X: [MM, DD], W: [DD, DD] row-major (so this is X @ W^T)
// 32x32 tile, 256 threads, 4 outputs/thread.
// ---------------------------------------------------------------------------
template<bool RES>
__global__ __launch_bounds__(256) void gemm_xwt(const float* __restrict__ X,
                                                const float* __restrict__ W,
                                                const float* __restrict__ Res,
                                                float* __restrict__ Out) {
    __shared__ float Xs[32][33];
    __shared__ float Ws[32][33];
    const int tx = threadIdx.x & 31;   // n within tile
    const int ty = threadIdx.x >> 5;   // 0..7 (m group)
    const int m0 = blockIdx.y * 32;
    const int n0 = blockIdx.x * 32;

    float acc[4] = {0.f, 0.f, 0.f, 0.f};

    for (int k0 = 0; k0 < DD; k0 += 32) {
#pragma unroll
        for (int r = 0; r < 4; r++) {
            int row = ty + r * 8;
            Xs[row][tx] = X[(size_t)(m0 + row) * DD + k0 + tx];
            Ws[row][tx] = W[(size_t)(n0 + row) * DD + k0 + tx];
        }
        __syncthreads();
#pragma unroll
        for (int kk = 0; kk < 32; kk++) {
            float wv = Ws[tx][kk];
#pragma unroll
            for (int r = 0; r < 4; r++)
                acc[r] += Xs[ty + r * 8][kk] * wv;
        }
        __syncthreads();
    }
#pragma unroll
    for (int r = 0; r < 4; r++) {
        size_t idx = (size_t)(m0 + ty + r * 8) * DD + n0 + tx;
        Out[idx] = RES ? (Res[idx] + acc[r]) : acc[r];
    }
}

// ---------------------------------------------------------------------------
// RoPE (full D=256 rotation, pair (j, j+128)), in-place.
// grid = BB*LL blocks, 128 threads.
// ---------------------------------------------------------------------------
__global__ __launch_bounds__(128) void rope_kernel(float* __restrict__ X) {
    const int row = blockIdx.x;        // b*LL + l
    const int l   = row & (LL - 1);
    const int j   = threadIdx.x;       // 0..127
    // inv_freq[j] = 10000^(-2j/256)
    float inv = expf(-((float)j / 128.0f) * 9.210340371976184f); // ln(10000)
    float f = (float)l * inv;
    float c = cosf(f);
    float s = sinf(f);
    float* p = X + (size_t)row * DD;
    float x1 = p[j];
    float x2 = p[j + 128];
    p[j]       = x1 * c - x2 * s;
    p[j + 128] = x2 * c + x1 * s;
}

// ---------------------------------------------------------------------------
// Attention for one (b, h, q): scores over 2048 keys in LDS, softmax,
// PV accumulate. T[b,q, h*32+i] = softmax(q.K^T * dh^-0.5) @ V
// block = 256 threads, grid = (LL, NH, BB)
// ---------------------------------------------------------------------------
__global__ __launch_bounds__(256) void attn_kernel(const float* __restrict__ Q,
                                                   const float* __restrict__ K,
                                                   const float* __restrict__ V,
                                                   float* __restrict__ T) {
    __shared__ float sc[LL];          // 8 KB scores
    __shared__ float qs[DHH];
    __shared__ float red[8];
    __shared__ float part[8][DHH];

    const int qi = blockIdx.x;
    const int h  = blockIdx.y;
    const int b  = blockIdx.z;
    const int t  = threadIdx.x;       // 0..255
    const float scale = 0.17677669529663687f;  // 32^-0.5

    if (t < DHH) qs[t] = Q[((size_t)(b * LL + qi)) * DD + h * DHH + t];
    __syncthreads();

    // --- scores ---
    float lmax = -1e30f;
#pragma unroll
    for (int j = 0; j < 8; j++) {
        int k = t + j * 256;
        const float4* krow4 = (const float4*)(K + ((size_t)(b * LL + k)) * DD + h * DHH);
        float s = 0.f;
#pragma unroll
        for (int i = 0; i < 8; i++) {
            float4 kv = krow4[i];
            s += qs[i*4+0]*kv.x + qs[i*4+1]*kv.y + qs[i*4+2]*kv.z + qs[i*4+3]*kv.w;
        }
        s *= scale;
        sc[k] = s;
        lmax = fmaxf(lmax, s);
    }
    // wave (64) reduce max, then across 4 waves
#pragma unroll
    for (int off = 32; off; off >>= 1) lmax = fmaxf(lmax, __shfl_xor(lmax, off));
    if ((t & 63) == 0) red[t >> 6] = lmax;
    __syncthreads();
    float gmax = fmaxf(fmaxf(red[0], red[1]), fmaxf(red[2], red[3]));

    // --- exp + sum ---
    float lsum = 0.f;
#pragma unroll
    for (int j = 0; j < 8; j++) {
        int k = t + j * 256;
        float e = __expf(sc[k] - gmax);
        sc[k] = e;
        lsum += e;
    }
#pragma unroll
    for (int off = 32; off; off >>= 1) lsum += __shfl_xor(lsum, off);
    if ((t & 63) == 0) red[4 + (t >> 6)] = lsum;
    __syncthreads();
    float gsum = red[4] + red[5] + red[6] + red[7];

    // --- PV: 8 groups of 32 lanes; group g handles keys [256g, 256g+256) ---
    const int g    = t >> 5;
    const int lane = t & 31;
    float acc = 0.f;
    const float* vbase = V + ((size_t)b * LL) * DD + h * DHH + lane;
    int kend = g * 256 + 256;
    for (int k = g * 256; k < kend; k++) {
        acc += sc[k] * vbase[(size_t)k * DD];
    }
    part[g][lane] = acc;
    __syncthreads();

    if (t < DHH) {
        float s = 0.f;
#pragma unroll
        for (int gg = 0; gg < 8; gg++) s += part[gg][t];
        T[((size_t)(b * LL + qi)) * DD + h * DHH + t] = s / gsum;
    }
}

// ---------------------------------------------------------------------------
// Launch: layer loop on host, all kernels on `stream`.
// d_out = [f0 ; f1] live buffers. d_ws: Q, K, V, T (4 MB each = 16 MB).
// ---------------------------------------------------------------------------
extern "C" void kernel_launch(void* const* d_in, const int* in_sizes, int n_in,
                              void* d_out, int out_size, void* d_ws, size_t ws_size,
                              hipStream_t stream) {
    const float* f0_in = (const float*)d_in[0];
    const float* f1_in = (const float*)d_in[1];
    const float* Wq = (const float*)d_in[2];
    const float* Wk = (const float*)d_in[3];
    const float* Wv = (const float*)d_in[4];
    const float* Wo = (const float*)d_in[5];

    float* F0 = (float*)d_out;                 // B*L*D
    float* F1 = F0 + (size_t)MM * DD;

    float* Qb = (float*)d_ws;
    float* Kb = Qb + (size_t)MM * DD;
    float* Vb = Kb + (size_t)MM * DD;
    float* Tb = Vb + (size_t)MM * DD;

    const size_t fbytes = (size_t)MM * DD * sizeof(float);
    hipMemcpyAsync(F0, f0_in, fbytes, hipMemcpyDeviceToDevice, stream);
    hipMemcpyAsync(F1, f1_in, fbytes, hipMemcpyDeviceToDevice, stream);

    dim3 gB(256);
    dim3 gG(DD / 32, MM / 32);       // (8, 128)
    dim3 aG(LL, NH, BB);             // (2048, 8, 2)

    for (int i = 0; i < NLAYERS; i++) {
        const float* wq = Wq + (size_t)i * DD * DD;
        const float* wk = Wk + (size_t)i * DD * DD;
        const float* wv = Wv + (size_t)i * DD * DD;
        const float* wo = Wo + (size_t)i * DD * DD;
        const bool self = (i % 2 == 0);

        for (int s = 0; s < 2; s++) {
            float* x   = s ? F1 : F0;
            float* src = self ? x : (s ? F0 : F1);   // cross: f1 attends UPDATED f0

            gemm_xwt<false><<<gG, gB, 0, stream>>>(x,   wq, nullptr, Qb);
            gemm_xwt<false><<<gG, gB, 0, stream>>>(src, wk, nullptr, Kb);
            gemm_xwt<false><<<gG, gB, 0, stream>>>(src, wv, nullptr, Vb);
            if (self) {
                rope_kernel<<<MM, 128, 0, stream>>>(Qb);
                rope_kernel<<<MM, 128, 0, stream>>>(Kb);
            }
            attn_kernel<<<aG, 256, 0, stream>>>(Qb, Kb, Vb, Tb);
            gemm_xwt<true><<<gG, gB, 0, stream>>>(Tb, wo, x, x);   // x += T @ Wo^T
        }
    }
}

// Round 2
// 996.770 us; speedup vs baseline: 31.7408x; 31.7408x over previous
//
#include <hip/hip_runtime.h>

#define BB   2
#define LL   2048
#define DD   256
#define NH   8
#define DHH  32
#define MM   (BB*LL)
#define NLAYERS 8
#define MMDD ((size_t)MM*DD)

typedef __attribute__((ext_vector_type(8))) short  short8;
typedef __attribute__((ext_vector_type(4))) float  f32x4;
typedef __attribute__((ext_vector_type(4))) unsigned int u32x4;
typedef __attribute__((ext_vector_type(2))) unsigned int u32x2;

__device__ inline unsigned short f2bf(float x) {
    unsigned int b = __builtin_bit_cast(unsigned int, x);
    b += 0x7FFFu + ((b >> 16) & 1u);          // RTNE
    return (unsigned short)(b >> 16);
}
__device__ inline float bf2f(unsigned short h) {
    unsigned int b = ((unsigned int)h) << 16;
    return __builtin_bit_cast(float, b);
}
__device__ inline f32x4 mfma16(short8 a, short8 b, f32x4 c) {
    return __builtin_amdgcn_mfma_f32_16x16x32_bf16(a, b, c, 0, 0, 0);
}

// ---------------------------------------------------------------------------
// MFMA GEMM: Out[m,n] = (+Res) + sum_k X[m,k]*W[n,k]   (X fp32, W fp32)
// 64x64 tile, full K=256 staged as bf16 in LDS (64 KB), 4 waves.
// MODE: 0 fp32 out, 1 fp32 out + residual, 2 bf16 out, 3 bf16 transposed-V out
// ---------------------------------------------------------------------------
template<int MODE>
__global__ __launch_bounds__(256) void gemm64(const float* __restrict__ X,
                                              const float* __restrict__ W,
                                              const float* Res, float* OutF,
                                              unsigned short* __restrict__ OutH) {
    __shared__ unsigned short Xs[64 * 256];   // slot(m,c)=m*32+(c^(m&7)), 8 bf16/slot
    __shared__ unsigned short Ws[64 * 256];
    const int tid = threadIdx.x;
    const int m0 = blockIdx.y * 64, n0 = blockIdx.x * 64;

#pragma unroll
    for (int kc = 0; kc < 8; kc++) {
        int ch = tid + kc * 256;              // 0..2047
        int r = ch >> 5, c = ch & 31;
        const f32x4* gx = (const f32x4*)(X + (size_t)(m0 + r) * 256 + c * 8);
        const f32x4* gw = (const f32x4*)(W + (size_t)(n0 + r) * 256 + c * 8);
        f32x4 x0 = gx[0], x1 = gx[1];
        f32x4 w0 = gw[0], w1 = gw[1];
        u32x4 px, pw;
        px.x = f2bf(x0.x) | ((unsigned)f2bf(x0.y) << 16);
        px.y = f2bf(x0.z) | ((unsigned)f2bf(x0.w) << 16);
        px.z = f2bf(x1.x) | ((unsigned)f2bf(x1.y) << 16);
        px.w = f2bf(x1.z) | ((unsigned)f2bf(x1.w) << 16);
        pw.x = f2bf(w0.x) | ((unsigned)f2bf(w0.y) << 16);
        pw.y = f2bf(w0.z) | ((unsigned)f2bf(w0.w) << 16);
        pw.z = f2bf(w1.x) | ((unsigned)f2bf(w1.y) << 16);
        pw.w = f2bf(w1.z) | ((unsigned)f2bf(w1.w) << 16);
        int slot = r * 32 + (c ^ (r & 7));
        *(u32x4*)&Xs[slot * 8] = px;
        *(u32x4*)&Ws[slot * 8] = pw;
    }
    __syncthreads();

    const int lane = tid & 63, w = tid >> 6;
    const int ql = lane & 15, gq = lane >> 4;
    f32x4 z = {0.f, 0.f, 0.f, 0.f};
    f32x4 acc[4] = {z, z, z, z};
#pragma unroll
    for (int ks = 0; ks < 8; ks++) {
        int cc = ks * 4 + gq;
        short8 af = *(const short8*)&Xs[((w * 16 + ql) * 32 + (cc ^ (ql & 7))) * 8];
#pragma unroll
        for (int nf = 0; nf < 4; nf++) {
            short8 bf = *(const short8*)&Ws[((nf * 16 + ql) * 32 + (cc ^ (ql & 7))) * 8];
            acc[nf] = mfma16(af, bf, acc[nf]);
        }
    }
#pragma unroll
    for (int nf = 0; nf < 4; nf++) {
#pragma unroll
        for (int r = 0; r < 4; r++) {
            int mg = m0 + w * 16 + gq * 4 + r;
            int ng = n0 + nf * 16 + ql;
            float v = acc[nf][r];
            if constexpr (MODE == 0) {
                OutF[(size_t)mg * 256 + ng] = v;
            } else if constexpr (MODE == 1) {
                size_t i = (size_t)mg * 256 + ng;
                OutF[i] = Res[i] + v;
            } else if constexpr (MODE == 2) {
                OutH[(size_t)mg * 256 + ng] = f2bf(v);
            } else {
                int b = mg >> 11, key = mg & 2047;
                int hh = ng >> 5, dh = ng & 31;
                OutH[((size_t)((b * 8 + hh) * 32 + dh)) * 2048 + key] = f2bf(v);
            }
        }
    }
}

// ---------------------------------------------------------------------------
// RoPE cos/sin table: tab[pos*128+j] = {cos, sin}(pos * 10000^(-j/128))
// ---------------------------------------------------------------------------
__global__ __launch_bounds__(128) void rope_table_k(float* __restrict__ tab) {
    int p = blockIdx.x, j = threadIdx.x;
    float inv = __expf(-((float)j / 128.f) * 9.210340371976184f);
    float f = (float)p * inv;
    float s, c;
    sincosf(f, &s, &c);
    tab[(size_t)(p * 128 + j) * 2 + 0] = c;
    tab[(size_t)(p * 128 + j) * 2 + 1] = s;
}

// RoPE: read fp32 src, rotate, write bf16 dst. grid=MM, block=128.
__global__ __launch_bounds__(128) void rope_f32_bf16(const float* __restrict__ S,
                                                     unsigned short* __restrict__ Dst,
                                                     const float* __restrict__ tab) {
    int m = blockIdx.x, j = threadIdx.x;
    int pos = m & (LL - 1);
    float c = tab[(size_t)(pos * 128 + j) * 2 + 0];
    float s = tab[(size_t)(pos * 128 + j) * 2 + 1];
    const float* sp = S + (size_t)m * 256;
    unsigned short* dp = Dst + (size_t)m * 256;
    float a = sp[j], b = sp[j + 128];
    dp[j]       = f2bf(a * c - b * s);
    dp[j + 128] = f2bf(b * c + a * s);
}

// ---------------------------------------------------------------------------
// Flash MFMA attention. Q,K bf16 [M,256] (head h at col h*32); Vt bf16
// [b,h,dh=32,key=2048]; T fp32 [M,256]. Swapped orientation:
//   S^T = mfma(A=K_tile, B=Q)   -> lane: q=l&15 (col), key=4*(l>>4)+r (row)
//   O^T = mfma(A=Vt,     B=P^T) -> lane: q=l&15 (col), dh =4*(l>>4)+r (row)
// so running m,l and the O rescale are fully in-lane.
// grid=(32, 8, 2), block=256 (4 waves x 16 queries).
// ---------------------------------------------------------------------------
__global__ __launch_bounds__(256) void attn_mfma(const unsigned short* __restrict__ Q,
                                                 const unsigned short* __restrict__ K,
                                                 const unsigned short* __restrict__ Vt,
                                                 float* __restrict__ T) {
    __shared__ unsigned short K_lds[64 * 32];     // slot(key,g)=key*4+g (bank-balanced)
    __shared__ unsigned short V_lds[32 * 64];     // slot(dh,c)=dh*8+(c^(dh&7))
    __shared__ unsigned short P_lds[4][16 * 64];  // per-wave; slot(q,c)=q*8+(c^(q&7))

    const int tid = threadIdx.x;
    const int lane = tid & 63, w = tid >> 6;
    const int ql = lane & 15, gq = lane >> 4;
    const int h = blockIdx.y, b = blockIdx.z;
    const int q0 = blockIdx.x * 64 + w * 16;
    const size_t bL = (size_t)b * LL;
    const int bh = b * 8 + h;
    const float scale = 0.17677669529663687f;     // 32^-0.5

    short8 qf = *(const short8*)&Q[(bL + q0 + ql) * 256 + h * 32 + gq * 8];

    f32x4 z = {0.f, 0.f, 0.f, 0.f};
    f32x4 o0 = z, o1 = z;
    float mrun = -1e30f, lrun = 0.f;

    // staging assignment (256 threads)
    const int skey = tid >> 2, sg = tid & 3;                    // K: 64 keys x 4 chunks
    const int sdh = tid >> 3, sc = tid & 7;                     // V: 32 dh x 8 chunks
    const size_t kgbase = (bL + skey) * 256 + h * 32 + sg * 8;
    const size_t vgbase = ((size_t)bh * 32 + sdh) * 2048 + sc * 8;
    const int vslot = sdh * 8 + (sc ^ (sdh & 7));

    u32x4 kreg = *(const u32x4*)&K[kgbase];
    u32x4 vreg = *(const u32x4*)&Vt[vgbase];

    for (int t = 0; t < 32; t++) {
        if (t > 0) __syncthreads();
        *(u32x4*)&K_lds[tid * 8]   = kreg;
        *(u32x4*)&V_lds[vslot * 8] = vreg;
        __syncthreads();
        if (t + 1 < 32) {   // prefetch next tile into regs (overlaps compute)
            kreg = *(const u32x4*)&K[kgbase + (size_t)(t + 1) * 64 * 256];
            vreg = *(const u32x4*)&Vt[vgbase + (size_t)(t + 1) * 64];
        }
        // --- S^T subtiles: keys 16j+4gq+r (row), query ql (col)
        f32x4 st[4];
#pragma unroll
        for (int j = 0; j < 4; j++) {
            short8 kf = *(const short8*)&K_lds[((16 * j + ql) * 4 + gq) * 8];
            st[j] = mfma16(kf, qf, z);
        }
        // --- online softmax (per-lane state for q = ql)
        float tm = -1e30f;
#pragma unroll
        for (int j = 0; j < 4; j++)
#pragma unroll
            for (int r = 0; r < 4; r++) {
                st[j][r] *= scale;
                tm = fmaxf(tm, st[j][r]);
            }
        tm = fmaxf(tm, __shfl_xor(tm, 16));
        tm = fmaxf(tm, __shfl_xor(tm, 32));
        float mnew = fmaxf(mrun, tm);
        float corr = __expf(mrun - mnew);
        float tsum = 0.f;
#pragma unroll
        for (int j = 0; j < 4; j++)
#pragma unroll
            for (int r = 0; r < 4; r++) {
                float p = __expf(st[j][r] - mnew);
                st[j][r] = p;
                tsum += p;
            }
        tsum += __shfl_xor(tsum, 16);
        tsum += __shfl_xor(tsum, 32);
        lrun = lrun * corr + tsum;
        mrun = mnew;
        o0 *= corr;
        o1 *= corr;
        // --- P^T -> wave-private LDS (keys 16j+4gq.. packed as 4 bf16)
#pragma unroll
        for (int j = 0; j < 4; j++) {
            unsigned lo = f2bf(st[j][0]) | ((unsigned)f2bf(st[j][1]) << 16);
            unsigned hi = f2bf(st[j][2]) | ((unsigned)f2bf(st[j][3]) << 16);
            int cc = 2 * j + (gq >> 1);
            int slot = ql * 8 + (cc ^ (ql & 7));
            u32x2 pv = {lo, hi};
            *(u32x2*)&P_lds[w][slot * 8 + (gq & 1) * 4] = pv;
        }
        // --- PV: O^T += Vt * P^T (two 32-key steps, two dh halves)
#pragma unroll
        for (int ks = 0; ks < 2; ks++) {
            int cc = 4 * ks + gq;
            short8 pf  = *(const short8*)&P_lds[w][(ql * 8 + (cc ^ (ql & 7))) * 8];
            short8 vf0 = *(const short8*)&V_lds[((ql)      * 8 + (cc ^ (ql & 7))) * 8];
            short8 vf1 = *(const short8*)&V_lds[((16 + ql) * 8 + (cc ^ (ql & 7))) * 8];
            o0 = mfma16(vf0, pf, o0);
            o1 = mfma16(vf1, pf, o1);
        }
    }
    float rinv = 1.f / lrun;
    f32x4 r0 = o0 * rinv, r1 = o1 * rinv;
    *(f32x4*)&T[(bL + q0 + ql) * 256 + h * 32 + gq * 4]      = r0;
    *(f32x4*)&T[(bL + q0 + ql) * 256 + h * 32 + 16 + gq * 4] = r1;
}

// ---------------------------------------------------------------------------
extern "C" void kernel_launch(void* const* d_in, const int* in_sizes, int n_in,
                              void* d_out, int out_size, void* d_ws, size_t ws_size,
                              hipStream_t stream) {
    const float* f0_in = (const float*)d_in[0];
    const float* f1_in = (const float*)d_in[1];
    const float* Wq = (const float*)d_in[2];
    const float* Wk = (const float*)d_in[3];
    const float* Wv = (const float*)d_in[4];
    const float* Wo = (const float*)d_in[5];

    float* F0 = (float*)d_out;
    float* F1 = F0 + MMDD;

    unsigned short* Qb = (unsigned short*)d_ws;   // 2MB bf16
    unsigned short* Kb = Qb + MMDD;               // 2MB
    unsigned short* Vt = Kb + MMDD;               // 2MB (b,h,dh,key)
    float* Tb  = (float*)(Vt + MMDD);             // 4MB fp32 (also Q-fp32 temp)
    float* tab = Tb + MMDD;                       // 2MB cos/sin table
    float* Ftmp = tab + (size_t)LL * 128 * 2;     // 4MB fp32 (K-fp32 temp)

    const size_t fbytes = MMDD * sizeof(float);
    hipMemcpyAsync(F0, f0_in, fbytes, hipMemcpyDeviceToDevice, stream);
    hipMemcpyAsync(F1, f1_in, fbytes, hipMemcpyDeviceToDevice, stream);
    rope_table_k<<<LL, 128, 0, stream>>>(tab);

    dim3 gG(4, 64);            // 64x64 tiles over 4096x256
    dim3 aG(32, NH, BB);

    for (int i = 0; i < NLAYERS; i++) {
        const float* wq = Wq + (size_t)i * DD * DD;
        const float* wk = Wk + (size_t)i * DD * DD;
        const float* wv = Wv + (size_t)i * DD * DD;
        const float* wo = Wo + (size_t)i * DD * DD;
        const bool self = (i % 2 == 0);

        for (int s = 0; s < 2; s++) {
            float* x   = s ? F1 : F0;
            float* src = self ? x : (s ? F0 : F1);   // cross: f1 attends UPDATED f0

            if (self) {
                gemm64<0><<<gG, 256, 0, stream>>>(x,   wq, nullptr, Tb,   nullptr);
                rope_f32_bf16<<<MM, 128, 0, stream>>>(Tb, Qb, tab);
                gemm64<0><<<gG, 256, 0, stream>>>(src, wk, nullptr, Ftmp, nullptr);
                rope_f32_bf16<<<MM, 128, 0, stream>>>(Ftmp, Kb, tab);
            } else {
                gemm64<2><<<gG, 256, 0, stream>>>(x,   wq, nullptr, nullptr, Qb);
                gemm64<2><<<gG, 256, 0, stream>>>(src, wk, nullptr, nullptr, Kb);
            }
            gemm64<3><<<gG, 256, 0, stream>>>(src, wv, nullptr, nullptr, Vt);
            attn_mfma<<<aG, 256, 0, stream>>>(Qb, Kb, Vt, Tb);
            gemm64<1><<<gG, 256, 0, stream>>>(Tb, wo, x, x, nullptr);
        }
    }
}

// Round 3
// 748.163 us; speedup vs baseline: 42.2880x; 1.3323x over previous
//
#include <hip/hip_runtime.h>

#define BB   2
#define LL   2048
#define DD   256
#define NH   8
#define MM   (BB*LL)
#define NLAYERS 8
#define MMDD ((size_t)MM*DD)

typedef unsigned short ushort_t;
typedef __attribute__((ext_vector_type(8))) short  short8;
typedef __attribute__((ext_vector_type(4))) float  f32x4;
typedef __attribute__((ext_vector_type(4))) unsigned int u32x4;
typedef __attribute__((ext_vector_type(2))) unsigned int u32x2;

__device__ __forceinline__ f32x4 mfma16(short8 a, short8 b, f32x4 c) {
    return __builtin_amdgcn_mfma_f32_16x16x32_bf16(a, b, c, 0, 0, 0);
}
// packed f32x2 -> bf16x2 (RTNE), one instruction
__device__ __forceinline__ unsigned cvtpk(float lo, float hi) {
    unsigned r;
    asm volatile("v_cvt_pk_bf16_f32 %0, %1, %2" : "=v"(r) : "v"(lo), "v"(hi));
    return r;
}
// async global->LDS, 16B per lane, dest = wave-uniform base + lane*16
__device__ __forceinline__ void gll16(const void* gsrc, void* ldst) {
    __builtin_amdgcn_global_load_lds(
        (const __attribute__((address_space(1))) unsigned int*)gsrc,
        (__attribute__((address_space(3))) unsigned int*)ldst, 16, 0, 0);
}

// ---------------------------------------------------------------------------
// fp32 -> bf16 bulk convert, 8 elems/thread
// ---------------------------------------------------------------------------
__global__ __launch_bounds__(256) void convbf(const float* __restrict__ in,
                                              ushort_t* __restrict__ out, int n8) {
    int i = blockIdx.x * 256 + threadIdx.x;
    if (i >= n8) return;
    const f32x4* p = (const f32x4*)(in + (size_t)i * 8);
    f32x4 a = p[0], b = p[1];
    u32x4 o = {cvtpk(a.x, a.y), cvtpk(a.z, a.w), cvtpk(b.x, b.y), cvtpk(b.z, b.w)};
    *(u32x4*)&out[(size_t)i * 8] = o;
}

// ---------------------------------------------------------------------------
// RoPE table: tab[pos*256 + j] = cos, tab[pos*256 + 128 + j] = sin
// ---------------------------------------------------------------------------
__global__ __launch_bounds__(128) void rtab(float* __restrict__ tab) {
    int p = blockIdx.x, j = threadIdx.x;
    float inv = __expf(-((float)j / 128.f) * 9.210340371976184f);
    float s, c;
    sincosf((float)p * inv, &s, &c);
    tab[(size_t)p * 256 + j]       = c;
    tab[(size_t)p * 256 + 128 + j] = s;
}

// RoPE: fp32 src -> rotate -> bf16 dst. 8 rows/block, 4 pairs/thread.
__global__ __launch_bounds__(256) void rope2(const float* __restrict__ S,
                                             ushort_t* __restrict__ Dst,
                                             const float* __restrict__ tab) {
    int t = threadIdx.x;
    int row = blockIdx.x * 8 + (t >> 5);
    int jj = (t & 31) * 4;
    int pos = row & (LL - 1);
    f32x4 a = *(const f32x4*)&S[(size_t)row * 256 + jj];
    f32x4 b = *(const f32x4*)&S[(size_t)row * 256 + 128 + jj];
    f32x4 c = *(const f32x4*)&tab[(size_t)pos * 256 + jj];
    f32x4 s = *(const f32x4*)&tab[(size_t)pos * 256 + 128 + jj];
    f32x4 o1 = a * c - b * s;
    f32x4 o2 = b * c + a * s;
    u32x2 p1 = {cvtpk(o1.x, o1.y), cvtpk(o1.z, o1.w)};
    u32x2 p2 = {cvtpk(o2.x, o2.y), cvtpk(o2.z, o2.w)};
    *(u32x2*)&Dst[(size_t)row * 256 + jj]       = p1;
    *(u32x2*)&Dst[(size_t)row * 256 + 128 + jj] = p2;
}

// ---------------------------------------------------------------------------
// bf16 MFMA GEMM: Out[m,n] = (+Res) + sum_k X[m,k]*W[n,k]; X,W bf16.
// 64x64 tile, K=256 staged via global_load_lds with inverse-swizzled source.
// LDS slot(r, x) holds global chunk (r, x ^ (r&7)); reads XOR the same way.
// MODE: 0 fp32 out | 1 fp32 residual + bf16 dual | 2 bf16 out | 3 bf16 V^T out
// ---------------------------------------------------------------------------
template<int MODE>
__global__ __launch_bounds__(256) void gemm_b(const ushort_t* __restrict__ X,
                                              const ushort_t* __restrict__ W,
                                              const float* Res, float* OutF,
                                              ushort_t* __restrict__ OutH) {
    __shared__ ushort_t Xs[64 * 256];
    __shared__ ushort_t Ws[64 * 256];
    const int tid = threadIdx.x, ln = tid & 63, w = tid >> 6;
    const int m0 = blockIdx.y * 64, n0 = blockIdx.x * 64;

#pragma unroll
    for (int i = 0; i < 8; i++) {
        int cg = w * 8 + i;                 // chunk-group 0..31 (64 chunks each)
        int c = cg * 64 + ln;               // chunk id 0..2047
        int r = c >> 5, x = c & 31;
        int xs = x ^ (r & 7);               // inverse swizzle on global source
        gll16(X + (size_t)(m0 + r) * 256 + xs * 8, &Xs[cg * 512]);
        gll16(W + (size_t)(n0 + r) * 256 + xs * 8, &Ws[cg * 512]);
    }
    __syncthreads();                        // drains vmcnt

    const int ql = ln & 15, gq = ln >> 4;
    const int wm = w >> 1, wn = w & 1;      // wave -> 32x32 quadrant
    f32x4 z4 = {0.f, 0.f, 0.f, 0.f};
    f32x4 acc[2][2] = {{z4, z4}, {z4, z4}};
#pragma unroll
    for (int ks = 0; ks < 8; ks++) {
        int cc = ks * 4 + gq;
        int r0 = 32 * wm + ql, r1 = r0 + 16;
        int n0r = 32 * wn + ql, n1r = n0r + 16;
        short8 a0 = *(const short8*)&Xs[(r0 * 32 + (cc ^ (r0 & 7))) * 8];
        short8 a1 = *(const short8*)&Xs[(r1 * 32 + (cc ^ (r1 & 7))) * 8];
        short8 b0 = *(const short8*)&Ws[(n0r * 32 + (cc ^ (n0r & 7))) * 8];
        short8 b1 = *(const short8*)&Ws[(n1r * 32 + (cc ^ (n1r & 7))) * 8];
        acc[0][0] = mfma16(a0, b0, acc[0][0]);
        acc[0][1] = mfma16(a0, b1, acc[0][1]);
        acc[1][0] = mfma16(a1, b0, acc[1][0]);
        acc[1][1] = mfma16(a1, b1, acc[1][1]);
    }
#pragma unroll
    for (int mf = 0; mf < 2; mf++)
#pragma unroll
        for (int nf = 0; nf < 2; nf++)
#pragma unroll
            for (int r = 0; r < 4; r++) {
                int mg = m0 + 32 * wm + 16 * mf + gq * 4 + r;
                int ng = n0 + 32 * wn + 16 * nf + ql;
                float v = acc[mf][nf][r];
                if constexpr (MODE == 0) {
                    OutF[(size_t)mg * 256 + ng] = v;
                } else if constexpr (MODE == 1) {
                    size_t idx = (size_t)mg * 256 + ng;
                    float o = Res[idx] + v;
                    OutF[idx] = o;
                    OutH[idx] = (ushort_t)cvtpk(o, o);
                } else if constexpr (MODE == 2) {
                    OutH[(size_t)mg * 256 + ng] = (ushort_t)cvtpk(v, v);
                } else {
                    int bt = mg >> 11, key = mg & 2047;
                    int hh = ng >> 5, dh = ng & 31;
                    OutH[((size_t)(bt * 8 + hh) * 32 + dh) * 2048 + key] =
                        (ushort_t)cvtpk(v, v);
                }
            }
}

// ---------------------------------------------------------------------------
// Flash MFMA attention v2. Q,K bf16 [M,256]; Vt bf16 [Z,8,32,2048]; T bf16.
// Double-buffered K/V via global_load_lds, 1 barrier/tile, base-2 softmax,
// defer-max, cvt_pk P-packing. grid=(32, 8, Z), block=256.
// ---------------------------------------------------------------------------
__global__ __launch_bounds__(256) void attn2(const ushort_t* __restrict__ Q,
                                             const ushort_t* __restrict__ K,
                                             const ushort_t* __restrict__ Vt,
                                             ushort_t* __restrict__ T) {
    __shared__ ushort_t K_lds[2][64 * 32];     // slot(key,g)=key*4+g
    __shared__ ushort_t V_lds[2][32 * 64];     // slot(dh,x)=dh*8+x holds sc=x^(dh&7)
    __shared__ ushort_t P_lds[4][16 * 64];     // per-wave P^T, swizzled

    const int tid = threadIdx.x, ln = tid & 63, w = tid >> 6;
    const int ql = ln & 15, gq = ln >> 4;
    const int h = blockIdx.y, zz = blockIdx.z;
    const int q0 = blockIdx.x * 64 + w * 16;
    const size_t rb = (size_t)zz * 2048;
    const float cS = 0.2550500394f;            // 32^-0.5 * log2(e)

    short8 qf = *(const short8*)&Q[(rb + q0 + ql) * 256 + h * 32 + gq * 8];

    // staging addresses (chunk this lane fills, wave-uniform LDS base)
    const int ck = w * 64 + ln;
    const ushort_t* kg = K + (rb + (ck >> 2)) * 256 + h * 32 + (ck & 3) * 8;
    const int vdh = ck >> 3, vsc = (ck & 7) ^ (vdh & 7);
    const ushort_t* vg = Vt + ((size_t)(zz * 8 + h) * 32 + vdh) * 2048 + vsc * 8;

    gll16(kg, &K_lds[0][w * 512]);
    gll16(vg, &V_lds[0][w * 512]);

    f32x4 z4 = {0.f, 0.f, 0.f, 0.f};
    f32x4 o0 = z4, o1 = z4;
    float m2 = -1e30f, lrun = 0.f;

    for (int t = 0; t < 32; t++) {
        __syncthreads();                        // drains vmcnt: tile t landed
        const int cb = t & 1, nb = cb ^ 1;
        if (t + 1 < 32) {                       // prefetch t+1 into other buffer
            gll16(kg + (size_t)(t + 1) * 64 * 256, &K_lds[nb][w * 512]);
            gll16(vg + (size_t)(t + 1) * 64,       &V_lds[nb][w * 512]);
        }
        const ushort_t* KL = K_lds[cb];
        const ushort_t* VL = V_lds[cb];

        // S^T subtiles: key rows 16j+4gq+r, query col ql
        f32x4 st[4];
#pragma unroll
        for (int j = 0; j < 4; j++) {
            short8 kf = *(const short8*)&KL[((16 * j + ql) * 4 + gq) * 8];
            st[j] = mfma16(kf, qf, z4);
        }
        // online softmax in log2 domain
        float tm = -1e30f;
#pragma unroll
        for (int j = 0; j < 4; j++)
#pragma unroll
            for (int r = 0; r < 4; r++) tm = fmaxf(tm, st[j][r]);
        tm = fmaxf(tm, __shfl_xor(tm, 16));
        tm = fmaxf(tm, __shfl_xor(tm, 32));
        float m2t = tm * cS;
        if (!__all(m2t - m2 <= 8.0f)) {         // defer-max: rescale only if needed
            float m2n = fmaxf(m2, m2t);
            float corr = __builtin_amdgcn_exp2f(m2 - m2n);
            o0 *= corr; o1 *= corr; lrun *= corr;
            m2 = m2n;
        }
        float tsum = 0.f;
#pragma unroll
        for (int j = 0; j < 4; j++)
#pragma unroll
            for (int r = 0; r < 4; r++) {
                float p = __builtin_amdgcn_exp2f(__builtin_fmaf(st[j][r], cS, -m2));
                st[j][r] = p;
                tsum += p;
            }
        tsum += __shfl_xor(tsum, 16);
        tsum += __shfl_xor(tsum, 32);
        lrun += tsum;
        // P^T -> wave-private LDS (keys 16j+4gq..+3 for q=ql)
#pragma unroll
        for (int j = 0; j < 4; j++) {
            unsigned lo = cvtpk(st[j][0], st[j][1]);
            unsigned hi = cvtpk(st[j][2], st[j][3]);
            int cc = 2 * j + (gq >> 1);
            u32x2 pv = {lo, hi};
            *(u32x2*)&P_lds[w][(ql * 8 + (cc ^ (ql & 7))) * 8 + (gq & 1) * 4] = pv;
        }
        // O^T += Vt * P^T
#pragma unroll
        for (int ks = 0; ks < 2; ks++) {
            int cc = 4 * ks + gq;
            int sw = cc ^ (ql & 7);
            short8 pf  = *(const short8*)&P_lds[w][(ql * 8 + sw) * 8];
            short8 vf0 = *(const short8*)&VL[((ql)      * 8 + sw) * 8];
            short8 vf1 = *(const short8*)&VL[((16 + ql) * 8 + sw) * 8];
            o0 = mfma16(vf0, pf, o0);
            o1 = mfma16(vf1, pf, o1);
        }
    }
    float rinv = 1.0f / lrun;
    unsigned t0 = cvtpk(o0.x * rinv, o0.y * rinv);
    unsigned t1 = cvtpk(o0.z * rinv, o0.w * rinv);
    unsigned t2 = cvtpk(o1.x * rinv, o1.y * rinv);
    unsigned t3 = cvtpk(o1.z * rinv, o1.w * rinv);
    u32x2 w0 = {t0, t1}, w1 = {t2, t3};
    *(u32x2*)&T[(rb + q0 + ql) * 256 + h * 32 + gq * 4]      = w0;
    *(u32x2*)&T[(rb + q0 + ql) * 256 + h * 32 + 16 + gq * 4] = w1;
}

// ---------------------------------------------------------------------------
extern "C" void kernel_launch(void* const* d_in, const int* in_sizes, int n_in,
                              void* d_out, int out_size, void* d_ws, size_t ws_size,
                              hipStream_t stream) {
    const float* f0_in = (const float*)d_in[0];
    const float* f1_in = (const float*)d_in[1];
    const float* Wq = (const float*)d_in[2];
    const float* Wk = (const float*)d_in[3];
    const float* Wv = (const float*)d_in[4];
    const float* Wo = (const float*)d_in[5];

    float* F0 = (float*)d_out;
    float* F1 = F0 + MMDD;

    // workspace layout (bf16 regions are 2*MMDD shorts each)
    ushort_t* Fb  = (ushort_t*)d_ws;          // bf16 mirror of [F0;F1]
    ushort_t* Qb  = Fb  + 2 * MMDD;
    ushort_t* Kb  = Qb  + 2 * MMDD;
    ushort_t* Vtb = Kb  + 2 * MMDD;           // [Z,8,32,2048]
    ushort_t* Tbb = Vtb + 2 * MMDD;           // attn out bf16
    ushort_t* Wb  = Tbb + 2 * MMDD;           // 4 arrays x 8 x 256 x 256 bf16
    float*    Tf  = (float*)(Wb + 2 * MMDD);  // fp32 temp [8192,256]
    float*    tab = Tf + 2 * MMDD;            // rope table, LL*256 f32

    ushort_t* Wqb = Wb;
    ushort_t* Wkb = Wb + (size_t)NLAYERS * 65536;
    ushort_t* Wvb = Wb + (size_t)2 * NLAYERS * 65536;
    ushort_t* Wob = Wb + (size_t)3 * NLAYERS * 65536;

    const size_t fbytes = MMDD * sizeof(float);
    hipMemcpyAsync(F0, f0_in, fbytes, hipMemcpyDeviceToDevice, stream);
    hipMemcpyAsync(F1, f1_in, fbytes, hipMemcpyDeviceToDevice, stream);
    convbf<<<1024, 256, 0, stream>>>(F0, Fb, 262144);   // both streams (contig)
    convbf<<<256, 256, 0, stream>>>(Wq, Wqb, 65536);
    convbf<<<256, 256, 0, stream>>>(Wk, Wkb, 65536);
    convbf<<<256, 256, 0, stream>>>(Wv, Wvb, 65536);
    convbf<<<256, 256, 0, stream>>>(Wo, Wob, 65536);
    rtab<<<LL, 128, 0, stream>>>(tab);

    dim3 gFull(4, 128);   // M=8192 (batched self)
    dim3 gHalf(4, 64);    // M=4096 (per-stream cross)

    for (int i = 0; i < NLAYERS; i++) {
        const ushort_t* wq = Wqb + (size_t)i * 65536;
        const ushort_t* wk = Wkb + (size_t)i * 65536;
        const ushort_t* wv = Wvb + (size_t)i * 65536;
        const ushort_t* wo = Wob + (size_t)i * 65536;

        if ((i & 1) == 0) {
            // self layer: both streams batched (independent)
            gemm_b<0><<<gFull, 256, 0, stream>>>(Fb, wq, nullptr, Tf, nullptr);
            rope2<<<1024, 256, 0, stream>>>(Tf, Qb, tab);
            gemm_b<0><<<gFull, 256, 0, stream>>>(Fb, wk, nullptr, Tf, nullptr);
            rope2<<<1024, 256, 0, stream>>>(Tf, Kb, tab);
            gemm_b<3><<<gFull, 256, 0, stream>>>(Fb, wv, nullptr, nullptr, Vtb);
            attn2<<<dim3(32, NH, 4), 256, 0, stream>>>(Qb, Kb, Vtb, Tbb);
            gemm_b<1><<<gFull, 256, 0, stream>>>(Tbb, wo, F0, F0, Fb);
        } else {
            // cross layer: f1 attends UPDATED f0 -> sequential streams
            for (int s = 0; s < 2; s++) {
                const ushort_t* xb = Fb + (size_t)s * MMDD;
                const ushort_t* sb = Fb + (size_t)(1 - s) * MMDD;
                float* xf = s ? F1 : F0;
                ushort_t* xbw = (ushort_t*)xb;
                gemm_b<2><<<gHalf, 256, 0, stream>>>(xb, wq, nullptr, nullptr, Qb);
                gemm_b<2><<<gHalf, 256, 0, stream>>>(sb, wk, nullptr, nullptr, Kb);
                gemm_b<3><<<gHalf, 256, 0, stream>>>(sb, wv, nullptr, nullptr, Vtb);
                attn2<<<dim3(32, NH, 2), 256, 0, stream>>>(Qb, Kb, Vtb, Tbb);
                gemm_b<1><<<gHalf, 256, 0, stream>>>(Tbb, wo, xf, xf, xbw);
            }
        }
    }
}

// Round 4
// 677.550 us; speedup vs baseline: 46.6951x; 1.1042x over previous
//
#include <hip/hip_runtime.h>

#define BB   2
#define LL   2048
#define DD   256
#define NH   8
#define MM   (BB*LL)
#define NLAYERS 8
#define MMDD ((size_t)MM*DD)

typedef unsigned short ushort_t;
typedef __attribute__((ext_vector_type(8))) short  short8;
typedef __attribute__((ext_vector_type(4))) float  f32x4;
typedef __attribute__((ext_vector_type(4))) unsigned int u32x4;
typedef __attribute__((ext_vector_type(2))) unsigned int u32x2;

#define CSC 0.2550500394f   /* 32^-0.5 * log2(e), folded into Q */

__device__ __forceinline__ f32x4 mfma16(short8 a, short8 b, f32x4 c) {
    return __builtin_amdgcn_mfma_f32_16x16x32_bf16(a, b, c, 0, 0, 0);
}
__device__ __forceinline__ unsigned cvtpk(float lo, float hi) {
    unsigned r;
    asm volatile("v_cvt_pk_bf16_f32 %0, %1, %2" : "=v"(r) : "v"(lo), "v"(hi));
    return r;
}
__device__ __forceinline__ void gll16(const void* gsrc, void* ldst) {
    __builtin_amdgcn_global_load_lds(
        (const __attribute__((address_space(1))) unsigned int*)gsrc,
        (__attribute__((address_space(3))) unsigned int*)ldst, 16, 0, 0);
}

// ---------------------------------------------------------------------------
__global__ __launch_bounds__(256) void convbf(const float* __restrict__ in,
                                              ushort_t* __restrict__ out, int n8) {
    int i = blockIdx.x * 256 + threadIdx.x;
    if (i >= n8) return;
    const f32x4* p = (const f32x4*)(in + (size_t)i * 8);
    f32x4 a = p[0], b = p[1];
    u32x4 o = {cvtpk(a.x, a.y), cvtpk(a.z, a.w), cvtpk(b.x, b.y), cvtpk(b.z, b.w)};
    *(u32x4*)&out[(size_t)i * 8] = o;
}

__global__ __launch_bounds__(128) void rtab(float* __restrict__ tab) {
    int p = blockIdx.x, j = threadIdx.x;
    float inv = __expf(-((float)j / 128.f) * 9.210340371976184f);
    float s, c;
    sincosf((float)p * inv, &s, &c);
    tab[(size_t)p * 256 + j]       = c;
    tab[(size_t)p * 256 + 128 + j] = s;
}

// RoPE fp32 -> bf16; SC: multiply by CSC (Q path: fold softmax scale into Q)
template<int SC>
__global__ __launch_bounds__(256) void rope2(const float* __restrict__ S,
                                             ushort_t* __restrict__ Dst,
                                             const float* __restrict__ tab) {
    int t = threadIdx.x;
    int row = blockIdx.x * 8 + (t >> 5);
    int jj = (t & 31) * 4;
    int pos = row & (LL - 1);
    f32x4 a = *(const f32x4*)&S[(size_t)row * 256 + jj];
    f32x4 b = *(const f32x4*)&S[(size_t)row * 256 + 128 + jj];
    f32x4 c = *(const f32x4*)&tab[(size_t)pos * 256 + jj];
    f32x4 s = *(const f32x4*)&tab[(size_t)pos * 256 + 128 + jj];
    f32x4 o1 = a * c - b * s;
    f32x4 o2 = b * c + a * s;
    if (SC) { o1 *= CSC; o2 *= CSC; }
    u32x2 p1 = {cvtpk(o1.x, o1.y), cvtpk(o1.z, o1.w)};
    u32x2 p2 = {cvtpk(o2.x, o2.y), cvtpk(o2.z, o2.w)};
    *(u32x2*)&Dst[(size_t)row * 256 + jj]       = p1;
    *(u32x2*)&Dst[(size_t)row * 256 + 128 + jj] = p2;
}

// ---------------------------------------------------------------------------
// bf16 MFMA GEMM, 64x64 tile, K=256 via global_load_lds (swizzled source).
// MODE: 0 fp32 | 1 fp32 residual + bf16 dual | 2 bf16 | 3 bf16 V^T (coalesced)
//       4 bf16 * CSC (cross-Q)
// ---------------------------------------------------------------------------
template<int MODE>
__global__ __launch_bounds__(256) void gemm_b(const ushort_t* __restrict__ X,
                                              const ushort_t* __restrict__ W,
                                              const float* Res, float* OutF,
                                              ushort_t* __restrict__ OutH) {
    __shared__ ushort_t Xs[64 * 256];
    __shared__ ushort_t Ws[64 * 256];
    const int tid = threadIdx.x, ln = tid & 63, w = tid >> 6;
    const int m0 = blockIdx.y * 64, n0 = blockIdx.x * 64;

#pragma unroll
    for (int i = 0; i < 8; i++) {
        int cg = w * 8 + i;
        int c = cg * 64 + ln;
        int r = c >> 5, x = c & 31;
        int xs = x ^ (r & 7);
        gll16(X + (size_t)(m0 + r) * 256 + xs * 8, &Xs[cg * 512]);
        gll16(W + (size_t)(n0 + r) * 256 + xs * 8, &Ws[cg * 512]);
    }
    __syncthreads();

    const int ql = ln & 15, gq = ln >> 4;
    const int wm = w >> 1, wn = w & 1;
    f32x4 z4 = {0.f, 0.f, 0.f, 0.f};
    f32x4 acc[2][2] = {{z4, z4}, {z4, z4}};
#pragma unroll
    for (int ks = 0; ks < 8; ks++) {
        int cc = ks * 4 + gq;
        int r0 = 32 * wm + ql, r1 = r0 + 16;
        int n0r = 32 * wn + ql, n1r = n0r + 16;
        short8 a0 = *(const short8*)&Xs[(r0 * 32 + (cc ^ (r0 & 7))) * 8];
        short8 a1 = *(const short8*)&Xs[(r1 * 32 + (cc ^ (r1 & 7))) * 8];
        short8 b0 = *(const short8*)&Ws[(n0r * 32 + (cc ^ (n0r & 7))) * 8];
        short8 b1 = *(const short8*)&Ws[(n1r * 32 + (cc ^ (n1r & 7))) * 8];
        acc[0][0] = mfma16(a0, b0, acc[0][0]);
        acc[0][1] = mfma16(a0, b1, acc[0][1]);
        acc[1][0] = mfma16(a1, b0, acc[1][0]);
        acc[1][1] = mfma16(a1, b1, acc[1][1]);
    }

    if constexpr (MODE == 3) {
        // stage fp32 tile transposed in LDS, then coalesced bf16 stores
        float* scr = (float*)Xs;            // [64][65] f32 = 16.6 KB
        __syncthreads();
#pragma unroll
        for (int mf = 0; mf < 2; mf++)
#pragma unroll
            for (int nf = 0; nf < 2; nf++)
#pragma unroll
                for (int r = 0; r < 4; r++) {
                    int nloc = 32 * wn + 16 * nf + ql;
                    int mloc = 32 * wm + 16 * mf + 4 * gq + r;
                    scr[nloc * 65 + mloc] = acc[mf][nf][r];
                }
        __syncthreads();
        int nloc = tid >> 2, mc = (tid & 3) * 16;
        int ng = n0 + nloc, hh = ng >> 5, dh = ng & 31;
        int mg = m0 + mc;
        int bt = mg >> 11, key = mg & 2047;
        const float* s = &scr[nloc * 65 + mc];
        u32x4 o1 = {cvtpk(s[0], s[1]), cvtpk(s[2], s[3]),
                    cvtpk(s[4], s[5]), cvtpk(s[6], s[7])};
        u32x4 o2 = {cvtpk(s[8], s[9]), cvtpk(s[10], s[11]),
                    cvtpk(s[12], s[13]), cvtpk(s[14], s[15])};
        ushort_t* dst = &OutH[((size_t)(bt * 8 + hh) * 32 + dh) * 2048 + key];
        *(u32x4*)dst = o1;
        *(u32x4*)(dst + 8) = o2;
    } else {
#pragma unroll
        for (int mf = 0; mf < 2; mf++)
#pragma unroll
            for (int nf = 0; nf < 2; nf++)
#pragma unroll
                for (int r = 0; r < 4; r++) {
                    int mg = m0 + 32 * wm + 16 * mf + gq * 4 + r;
                    int ng = n0 + 32 * wn + 16 * nf + ql;
                    float v = acc[mf][nf][r];
                    if constexpr (MODE == 0) {
                        OutF[(size_t)mg * 256 + ng] = v;
                    } else if constexpr (MODE == 1) {
                        size_t idx = (size_t)mg * 256 + ng;
                        float o = Res[idx] + v;
                        OutF[idx] = o;
                        OutH[idx] = (ushort_t)cvtpk(o, o);
                    } else if constexpr (MODE == 2) {
                        OutH[(size_t)mg * 256 + ng] = (ushort_t)cvtpk(v, v);
                    } else {  // MODE 4
                        float vs = v * CSC;
                        OutH[(size_t)mg * 256 + ng] = (ushort_t)cvtpk(vs, vs);
                    }
                }
    }
}

// ---------------------------------------------------------------------------
// Flash MFMA attention v3: fixed-shift softmax (no max tracking), l via
// ones-MFMA, KV-split partials. Q pre-scaled by CSC.
// grid=(32, NH, z*SPLIT), block=256. Writes unnormalized Op (f32) and Lp.
// ---------------------------------------------------------------------------
template<int SPLIT>
__global__ __launch_bounds__(256) void attn3(const ushort_t* __restrict__ Q,
                                             const ushort_t* __restrict__ K,
                                             const ushort_t* __restrict__ Vt,
                                             float* __restrict__ Op,
                                             float* __restrict__ Lp, int mrows) {
    constexpr int KEYS = 2048 / SPLIT;
    constexpr int NT = KEYS / 64;
    __shared__ ushort_t K_lds[2][64 * 32];   // slot = g*64 + key (chunk-major)
    __shared__ ushort_t V_lds[2][32 * 64];   // slot(dh,x)=dh*8+x holds c=x^(dh&7)
    __shared__ ushort_t P_lds[4][16 * 64];

    const int tid = threadIdx.x, ln = tid & 63, w = tid >> 6;
    const int ql = ln & 15, gq = ln >> 4;
    const int h = blockIdx.y;
    const int bz = blockIdx.z, zz = bz / SPLIT, sp = bz % SPLIT;
    const int q0 = blockIdx.x * 64 + w * 16;
    const size_t rb = (size_t)zz * 2048;

    short8 qf = *(const short8*)&Q[(rb + q0 + ql) * 256 + h * 32 + gq * 8];

    // K staging: lane ln of wave w fills LDS slot w*64+ln  ->  (g=w, key=ln)
    const ushort_t* kg = K + (rb + sp * KEYS + ln) * 256 + h * 32 + w * 8;
    const int ck = w * 64 + ln, vdh = ck >> 3, vsc = (ck & 7) ^ (vdh & 7);
    const ushort_t* vg = Vt + ((size_t)(zz * 8 + h) * 32 + vdh) * 2048
                            + sp * KEYS + vsc * 8;

    gll16(kg, &K_lds[0][w * 512]);
    gll16(vg, &V_lds[0][w * 512]);

    const short os = (short)0x3F80;          // bf16 1.0
    const short8 ones = {os, os, os, os, os, os, os, os};
    f32x4 z4 = {0.f, 0.f, 0.f, 0.f};
    f32x4 o0 = z4, o1 = z4, lacc = z4;

    for (int t = 0; t < NT; t++) {
        __syncthreads();                     // tile t resident (drains vmcnt)
        const int cb = t & 1, nb = cb ^ 1;
        if (t + 1 < NT) {
            gll16(kg + (size_t)(t + 1) * 64 * 256, &K_lds[nb][w * 512]);
            gll16(vg + (t + 1) * 64,               &V_lds[nb][w * 512]);
        }
        const ushort_t* KL = K_lds[cb];
        const ushort_t* VL = V_lds[cb];

        f32x4 st[4];
#pragma unroll
        for (int j = 0; j < 4; j++) {
            short8 kf = *(const short8*)&KL[(gq * 64 + 16 * j + ql) * 8];
            st[j] = mfma16(kf, qf, z4);
        }
        // p = exp2(s)  (scale pre-folded into Q; fixed shift C=0)
#pragma unroll
        for (int j = 0; j < 4; j++)
#pragma unroll
            for (int r = 0; r < 4; r++)
                st[j][r] = __builtin_amdgcn_exp2f(st[j][r]);
#pragma unroll
        for (int j = 0; j < 4; j++) {
            unsigned lo = cvtpk(st[j][0], st[j][1]);
            unsigned hi = cvtpk(st[j][2], st[j][3]);
            int cc = 2 * j + (gq >> 1);
            u32x2 pv = {lo, hi};
            *(u32x2*)&P_lds[w][(ql * 8 + (cc ^ (ql & 7))) * 8 + (gq & 1) * 4] = pv;
        }
#pragma unroll
        for (int ks = 0; ks < 2; ks++) {
            int cc = 4 * ks + gq;
            int sw = cc ^ (ql & 7);
            short8 pf  = *(const short8*)&P_lds[w][(ql * 8 + sw) * 8];
            short8 vf0 = *(const short8*)&VL[((ql)      * 8 + sw) * 8];
            short8 vf1 = *(const short8*)&VL[((16 + ql) * 8 + sw) * 8];
            o0 = mfma16(vf0, pf, o0);
            o1 = mfma16(vf1, pf, o1);
            lacc = mfma16(ones, pf, lacc);   // row-sum of P (all rows equal)
        }
    }
    size_t row = rb + q0 + ql;
    float* ob = Op + (size_t)sp * mrows * 256 + row * 256 + h * 32;
    *(f32x4*)&ob[gq * 4]      = o0;
    *(f32x4*)&ob[16 + gq * 4] = o1;
    if (gq == 0)
        Lp[(size_t)sp * mrows * 8 + row * 8 + h] = lacc[0];
}

// combine: Out = bf16( sum_sp Op / sum_sp Lp ). 8 rows/block.
template<int SPLIT>
__global__ __launch_bounds__(256) void combine(const float* __restrict__ Op,
                                               const float* __restrict__ Lp,
                                               ushort_t* __restrict__ Out,
                                               int mrows) {
    int t = threadIdx.x;
    size_t r = (size_t)blockIdx.x * 8 + (t >> 5);
    int c0 = (t & 31) * 8, h = c0 >> 5;
    float l = 0.f;
    f32x4 a = {0.f, 0.f, 0.f, 0.f}, b = a;
#pragma unroll
    for (int sp = 0; sp < SPLIT; sp++) {
        l += Lp[(size_t)sp * mrows * 8 + r * 8 + h];
        a += *(const f32x4*)&Op[(size_t)sp * mrows * 256 + r * 256 + c0];
        b += *(const f32x4*)&Op[(size_t)sp * mrows * 256 + r * 256 + c0 + 4];
    }
    float inv = 1.f / l;
    u32x4 o = {cvtpk(a.x * inv, a.y * inv), cvtpk(a.z * inv, a.w * inv),
               cvtpk(b.x * inv, b.y * inv), cvtpk(b.z * inv, b.w * inv)};
    *(u32x4*)&Out[r * 256 + c0] = o;
}

// ---------------------------------------------------------------------------
extern "C" void kernel_launch(void* const* d_in, const int* in_sizes, int n_in,
                              void* d_out, int out_size, void* d_ws, size_t ws_size,
                              hipStream_t stream) {
    const float* f0_in = (const float*)d_in[0];
    const float* f1_in = (const float*)d_in[1];
    const float* Wq = (const float*)d_in[2];
    const float* Wk = (const float*)d_in[3];
    const float* Wv = (const float*)d_in[4];
    const float* Wo = (const float*)d_in[5];

    float* F0 = (float*)d_out;
    float* F1 = F0 + MMDD;

    ushort_t* Fb  = (ushort_t*)d_ws;              // 4 MB bf16 [f0;f1]
    ushort_t* Qb  = Fb  + 2 * MMDD;               // 4 MB
    ushort_t* Kb  = Qb  + 2 * MMDD;               // 4 MB (K, then combined T)
    ushort_t* Vtb = Kb  + 2 * MMDD;               // 4 MB
    ushort_t* Wb  = Vtb + 2 * MMDD;               // 4 MB bf16 weights
    float*    Opw = (float*)(Wb + 2 * MMDD);      // 16 MB partial O (and Tf alias)
    float*    Lpw = Opw + (size_t)4 * 1048576;    // 0.5 MB partial l
    float*    tab = Lpw + 131072;                 // 2 MB rope table
    float*    Tf  = Opw;                          // fp32 GEMM temp (dead pre-attn)

    ushort_t* Wqb = Wb;
    ushort_t* Wkb = Wb + (size_t)NLAYERS * 65536;
    ushort_t* Wvb = Wb + (size_t)2 * NLAYERS * 65536;
    ushort_t* Wob = Wb + (size_t)3 * NLAYERS * 65536;

    const size_t fbytes = MMDD * sizeof(float);
    hipMemcpyAsync(F0, f0_in, fbytes, hipMemcpyDeviceToDevice, stream);
    hipMemcpyAsync(F1, f1_in, fbytes, hipMemcpyDeviceToDevice, stream);
    convbf<<<1024, 256, 0, stream>>>(F0, Fb, 262144);
    convbf<<<256, 256, 0, stream>>>(Wq, Wqb, 65536);
    convbf<<<256, 256, 0, stream>>>(Wk, Wkb, 65536);
    convbf<<<256, 256, 0, stream>>>(Wv, Wvb, 65536);
    convbf<<<256, 256, 0, stream>>>(Wo, Wob, 65536);
    rtab<<<LL, 128, 0, stream>>>(tab);

    dim3 gFull(4, 128);    // M = 8192
    dim3 gHalf(4, 64);     // M = 4096

    for (int i = 0; i < NLAYERS; i++) {
        const ushort_t* wq = Wqb + (size_t)i * 65536;
        const ushort_t* wk = Wkb + (size_t)i * 65536;
        const ushort_t* wv = Wvb + (size_t)i * 65536;
        const ushort_t* wo = Wob + (size_t)i * 65536;

        if ((i & 1) == 0) {
            // self: both streams batched, z=4, SPLIT=2
            gemm_b<0><<<gFull, 256, 0, stream>>>(Fb, wq, nullptr, Tf, nullptr);
            rope2<1><<<1024, 256, 0, stream>>>(Tf, Qb, tab);     // Q * CSC
            gemm_b<0><<<gFull, 256, 0, stream>>>(Fb, wk, nullptr, Tf, nullptr);
            rope2<0><<<1024, 256, 0, stream>>>(Tf, Kb, tab);
            gemm_b<3><<<gFull, 256, 0, stream>>>(Fb, wv, nullptr, nullptr, Vtb);
            attn3<2><<<dim3(32, NH, 8), 256, 0, stream>>>(Qb, Kb, Vtb, Opw, Lpw, MM * 2);
            combine<2><<<1024, 256, 0, stream>>>(Opw, Lpw, Kb, MM * 2);
            gemm_b<1><<<gFull, 256, 0, stream>>>(Kb, wo, F0, F0, Fb);
        } else {
            // cross: Q for BOTH streams first (pre-update states), then
            // sequential passes (f1 attends updated f0). z=2, SPLIT=4.
            gemm_b<4><<<gFull, 256, 0, stream>>>(Fb, wq, nullptr, nullptr, Qb);
            for (int s = 0; s < 2; s++) {
                const ushort_t* sb = Fb + (size_t)(1 - s) * MMDD;
                float* xf = s ? F1 : F0;
                ushort_t* xbw = Fb + (size_t)s * MMDD;
                gemm_b<2><<<gHalf, 256, 0, stream>>>(sb, wk, nullptr, nullptr, Kb);
                gemm_b<3><<<gHalf, 256, 0, stream>>>(sb, wv, nullptr, nullptr, Vtb);
                attn3<4><<<dim3(32, NH, 8), 256, 0, stream>>>(Qb + (size_t)s * MMDD,
                                                              Kb, Vtb, Opw, Lpw, MM);
                combine<4><<<512, 256, 0, stream>>>(Opw, Lpw, Kb, MM);
                gemm_b<1><<<gHalf, 256, 0, stream>>>(Kb, wo, xf, xf, xbw);
            }
        }
    }
}

// Round 5
// 650.069 us; speedup vs baseline: 48.6691x; 1.0423x over previous
//
#include <hip/hip_runtime.h>

#define BB   2
#define LL   2048
#define DD   256
#define NH   8
#define MM   (BB*LL)
#define NLAYERS 8
#define MMDD ((size_t)MM*DD)

typedef unsigned short ushort_t;
typedef __attribute__((ext_vector_type(8))) short  short8;
typedef __attribute__((ext_vector_type(4))) float  f32x4;
typedef __attribute__((ext_vector_type(4))) unsigned int u32x4;
typedef __attribute__((ext_vector_type(2))) unsigned int u32x2;

#define CSC 0.2550500394f   /* 32^-0.5 * log2(e), folded into Q */

__device__ __forceinline__ f32x4 mfma16(short8 a, short8 b, f32x4 c) {
    return __builtin_amdgcn_mfma_f32_16x16x32_bf16(a, b, c, 0, 0, 0);
}
__device__ __forceinline__ unsigned cvtpk(float lo, float hi) {
    unsigned r;
    asm volatile("v_cvt_pk_bf16_f32 %0, %1, %2" : "=v"(r) : "v"(lo), "v"(hi));
    return r;
}
__device__ __forceinline__ float bf2f(unsigned short h) {
    return __builtin_bit_cast(float, ((unsigned)h) << 16);
}
__device__ __forceinline__ void gll16(const void* gsrc, void* ldst) {
    __builtin_amdgcn_global_load_lds(
        (const __attribute__((address_space(1))) unsigned int*)gsrc,
        (__attribute__((address_space(3))) unsigned int*)ldst, 16, 0, 0);
}

// ---------------------------------------------------------------------------
__global__ __launch_bounds__(256) void convbf(const float* __restrict__ in,
                                              ushort_t* __restrict__ out, int n8) {
    int i = blockIdx.x * 256 + threadIdx.x;
    if (i >= n8) return;
    const f32x4* p = (const f32x4*)(in + (size_t)i * 8);
    f32x4 a = p[0], b = p[1];
    u32x4 o = {cvtpk(a.x, a.y), cvtpk(a.z, a.w), cvtpk(b.x, b.y), cvtpk(b.z, b.w)};
    *(u32x4*)&out[(size_t)i * 8] = o;
}

__global__ __launch_bounds__(128) void rtab(float* __restrict__ tab) {
    int p = blockIdx.x, j = threadIdx.x;
    float inv = __expf(-((float)j / 128.f) * 9.210340371976184f);
    float s, c;
    sincosf((float)p * inv, &s, &c);
    tab[(size_t)p * 256 + j]       = c;
    tab[(size_t)p * 256 + 128 + j] = s;
}

// RoPE bf16 -> bf16; SC: multiply by CSC (Q path). 8 rows/block.
template<int SC>
__global__ __launch_bounds__(256) void rope3(const ushort_t* __restrict__ S,
                                             ushort_t* __restrict__ Dst,
                                             const float* __restrict__ tab) {
    int t = threadIdx.x;
    int row = blockIdx.x * 8 + (t >> 5);
    int jj = (t & 31) * 4;
    int pos = row & (LL - 1);
    u32x2 va = *(const u32x2*)&S[(size_t)row * 256 + jj];
    u32x2 vb = *(const u32x2*)&S[(size_t)row * 256 + 128 + jj];
    f32x4 a = {bf2f(va.x & 0xffff), bf2f(va.x >> 16),
               bf2f(va.y & 0xffff), bf2f(va.y >> 16)};
    f32x4 b = {bf2f(vb.x & 0xffff), bf2f(vb.x >> 16),
               bf2f(vb.y & 0xffff), bf2f(vb.y >> 16)};
    f32x4 c = *(const f32x4*)&tab[(size_t)pos * 256 + jj];
    f32x4 s = *(const f32x4*)&tab[(size_t)pos * 256 + 128 + jj];
    f32x4 o1 = a * c - b * s;
    f32x4 o2 = b * c + a * s;
    if (SC) { o1 *= CSC; o2 *= CSC; }
    u32x2 p1 = {cvtpk(o1.x, o1.y), cvtpk(o1.z, o1.w)};
    u32x2 p2 = {cvtpk(o2.x, o2.y), cvtpk(o2.z, o2.w)};
    *(u32x2*)&Dst[(size_t)row * 256 + jj]       = p1;
    *(u32x2*)&Dst[(size_t)row * 256 + 128 + jj] = p2;
}

// ---------------------------------------------------------------------------
// bf16 MFMA GEMM, 64x64 tile, K=256, 1D grid with XCD swizzle: the 4 n-tiles
// sharing an X row-tile land on the same XCD (L2 reuse of X).
// MODE: 1 fp32 residual + bf16 dual | 2 bf16 | 3 bf16 V^T | 4 bf16*CSC
// ---------------------------------------------------------------------------
template<int MODE, int NTY>
__global__ __launch_bounds__(256) void gemm_b(const ushort_t* __restrict__ X,
                                              const ushort_t* __restrict__ W,
                                              const float* Res, float* OutF,
                                              ushort_t* __restrict__ OutH) {
    __shared__ ushort_t Xs[64 * 256];
    __shared__ ushort_t Ws[64 * 256];
    const int tid = threadIdx.x, ln = tid & 63, w = tid >> 6;
    // swizzle decode: f = xcd + 8*(bx + 4*byg), by = xcd*(NTY/8)+byg
    const int f = blockIdx.x;
    const int xcd = f & 7, s = f >> 3;
    const int bx = s & 3, byg = s >> 2;
    const int by = xcd * (NTY / 8) + byg;
    const int m0 = by * 64, n0 = bx * 64;

#pragma unroll
    for (int i = 0; i < 8; i++) {
        int cg = w * 8 + i;
        int c = cg * 64 + ln;
        int r = c >> 5, x = c & 31;
        int xs = x ^ (r & 7);
        gll16(X + (size_t)(m0 + r) * 256 + xs * 8, &Xs[cg * 512]);
        gll16(W + (size_t)(n0 + r) * 256 + xs * 8, &Ws[cg * 512]);
    }
    __syncthreads();

    const int ql = ln & 15, gq = ln >> 4;
    const int wm = w >> 1, wn = w & 1;
    f32x4 z4 = {0.f, 0.f, 0.f, 0.f};
    f32x4 acc[2][2] = {{z4, z4}, {z4, z4}};
#pragma unroll
    for (int ks = 0; ks < 8; ks++) {
        int cc = ks * 4 + gq;
        int r0 = 32 * wm + ql, r1 = r0 + 16;
        int n0r = 32 * wn + ql, n1r = n0r + 16;
        short8 a0 = *(const short8*)&Xs[(r0 * 32 + (cc ^ (r0 & 7))) * 8];
        short8 a1 = *(const short8*)&Xs[(r1 * 32 + (cc ^ (r1 & 7))) * 8];
        short8 b0 = *(const short8*)&Ws[(n0r * 32 + (cc ^ (n0r & 7))) * 8];
        short8 b1 = *(const short8*)&Ws[(n1r * 32 + (cc ^ (n1r & 7))) * 8];
        acc[0][0] = mfma16(a0, b0, acc[0][0]);
        acc[0][1] = mfma16(a0, b1, acc[0][1]);
        acc[1][0] = mfma16(a1, b0, acc[1][0]);
        acc[1][1] = mfma16(a1, b1, acc[1][1]);
    }

    if constexpr (MODE == 3) {
        float* scr = (float*)Xs;            // [64][65] f32
        __syncthreads();
#pragma unroll
        for (int mf = 0; mf < 2; mf++)
#pragma unroll
            for (int nf = 0; nf < 2; nf++)
#pragma unroll
                for (int r = 0; r < 4; r++) {
                    int nloc = 32 * wn + 16 * nf + ql;
                    int mloc = 32 * wm + 16 * mf + 4 * gq + r;
                    scr[nloc * 65 + mloc] = acc[mf][nf][r];
                }
        __syncthreads();
        int nloc = tid >> 2, mc = (tid & 3) * 16;
        int ng = n0 + nloc, hh = ng >> 5, dh = ng & 31;
        int mg = m0 + mc;
        int bt = mg >> 11, key = mg & 2047;
        const float* sc = &scr[nloc * 65 + mc];
        u32x4 o1 = {cvtpk(sc[0], sc[1]), cvtpk(sc[2], sc[3]),
                    cvtpk(sc[4], sc[5]), cvtpk(sc[6], sc[7])};
        u32x4 o2 = {cvtpk(sc[8], sc[9]), cvtpk(sc[10], sc[11]),
                    cvtpk(sc[12], sc[13]), cvtpk(sc[14], sc[15])};
        ushort_t* dst = &OutH[((size_t)(bt * 8 + hh) * 32 + dh) * 2048 + key];
        *(u32x4*)dst = o1;
        *(u32x4*)(dst + 8) = o2;
    } else {
#pragma unroll
        for (int mf = 0; mf < 2; mf++)
#pragma unroll
            for (int nf = 0; nf < 2; nf++)
#pragma unroll
                for (int r = 0; r < 4; r++) {
                    int mg = m0 + 32 * wm + 16 * mf + gq * 4 + r;
                    int ng = n0 + 32 * wn + 16 * nf + ql;
                    float v = acc[mf][nf][r];
                    if constexpr (MODE == 1) {
                        size_t idx = (size_t)mg * 256 + ng;
                        float o = Res[idx] + v;
                        OutF[idx] = o;
                        OutH[idx] = (ushort_t)cvtpk(o, o);
                    } else if constexpr (MODE == 2) {
                        OutH[(size_t)mg * 256 + ng] = (ushort_t)cvtpk(v, v);
                    } else {  // MODE 4
                        float vs = v * CSC;
                        OutH[(size_t)mg * 256 + ng] = (ushort_t)cvtpk(vs, vs);
                    }
                }
    }
}

// ---------------------------------------------------------------------------
// Flash MFMA attention v4: 32 queries/wave (two 16-q fragments sharing K/V
// reads), fixed-shift softmax, l via ones-MFMA, KV-split partials, XCD-group
// swizzle (16 q-blocks of one (h,z,sp) group -> one XCD).
// 1D grid of 1024 blocks, block=256 (4 waves x 32 q = 128 q/block).
// ---------------------------------------------------------------------------
template<int SPLIT>
__global__ __launch_bounds__(256) void attn4(const ushort_t* __restrict__ Q,
                                             const ushort_t* __restrict__ K,
                                             const ushort_t* __restrict__ Vt,
                                             float* __restrict__ Op,
                                             float* __restrict__ Lp, int mrows) {
    constexpr int KEYS = 2048 / SPLIT;
    constexpr int NT = KEYS / 64;
    __shared__ ushort_t K_lds[2][64 * 32];      // slot = g*64 + key
    __shared__ ushort_t V_lds[2][32 * 64];      // slot(dh,x)=dh*8+x, src c=x^(dh&7)
    __shared__ ushort_t P_lds[4][2][16 * 64];   // per-wave, per-qhalf

    const int tid = threadIdx.x, ln = tid & 63, w = tid >> 6;
    const int ql = ln & 15, gq = ln >> 4;
    // XCD-group decode: f = xcd + 8*(qb + 16*t8); group g = xcd + 8*t8
    const int f = blockIdx.x;
    const int xcd = f & 7, slot = f >> 3;
    const int qb = slot & 15, t8 = slot >> 4;
    const int g = xcd + 8 * t8;
    const int h = g & 7, zs = g >> 3;
    const int zz = zs / SPLIT, sp = zs % SPLIT;
    const int q0 = qb * 128 + w * 32;
    const size_t rb = (size_t)zz * 2048;

    short8 qfA = *(const short8*)&Q[(rb + q0 + ql) * 256 + h * 32 + gq * 8];
    short8 qfB = *(const short8*)&Q[(rb + q0 + 16 + ql) * 256 + h * 32 + gq * 8];

    const ushort_t* kg = K + (rb + sp * KEYS + ln) * 256 + h * 32 + w * 8;
    const int ck = w * 64 + ln, vdh = ck >> 3, vsc = (ck & 7) ^ (vdh & 7);
    const ushort_t* vg = Vt + ((size_t)(zz * 8 + h) * 32 + vdh) * 2048
                            + sp * KEYS + vsc * 8;

    gll16(kg, &K_lds[0][w * 512]);
    gll16(vg, &V_lds[0][w * 512]);

    const short os = (short)0x3F80;             // bf16 1.0
    const short8 ones = {os, os, os, os, os, os, os, os};
    f32x4 z4 = {0.f, 0.f, 0.f, 0.f};
    f32x4 o0A = z4, o1A = z4, o0B = z4, o1B = z4, laccA = z4, laccB = z4;

    for (int t = 0; t < NT; t++) {
        __syncthreads();                        // tile t resident
        const int cb = t & 1, nb = cb ^ 1;
        if (t + 1 < NT) {
            gll16(kg + (size_t)(t + 1) * 64 * 256, &K_lds[nb][w * 512]);
            gll16(vg + (t + 1) * 64,               &V_lds[nb][w * 512]);
        }
        const ushort_t* KL = K_lds[cb];
        const ushort_t* VL = V_lds[cb];

        f32x4 stA[4], stB[4];
#pragma unroll
        for (int j = 0; j < 4; j++) {
            short8 kf = *(const short8*)&KL[(gq * 64 + 16 * j + ql) * 8];
            stA[j] = mfma16(kf, qfA, z4);
            stB[j] = mfma16(kf, qfB, z4);
        }
#pragma unroll
        for (int j = 0; j < 4; j++)
#pragma unroll
            for (int r = 0; r < 4; r++) {
                stA[j][r] = __builtin_amdgcn_exp2f(stA[j][r]);
                stB[j][r] = __builtin_amdgcn_exp2f(stB[j][r]);
            }
#pragma unroll
        for (int j = 0; j < 4; j++) {
            int cc = 2 * j + (gq >> 1);
            int off = (ql * 8 + (cc ^ (ql & 7))) * 8 + (gq & 1) * 4;
            u32x2 pa = {cvtpk(stA[j][0], stA[j][1]), cvtpk(stA[j][2], stA[j][3])};
            u32x2 pb = {cvtpk(stB[j][0], stB[j][1]), cvtpk(stB[j][2], stB[j][3])};
            *(u32x2*)&P_lds[w][0][off] = pa;
            *(u32x2*)&P_lds[w][1][off] = pb;
        }
#pragma unroll
        for (int ks = 0; ks < 2; ks++) {
            int cc = 4 * ks + gq;
            int sw = cc ^ (ql & 7);
            short8 pfA = *(const short8*)&P_lds[w][0][(ql * 8 + sw) * 8];
            short8 pfB = *(const short8*)&P_lds[w][1][(ql * 8 + sw) * 8];
            short8 vf0 = *(const short8*)&VL[((ql)      * 8 + sw) * 8];
            short8 vf1 = *(const short8*)&VL[((16 + ql) * 8 + sw) * 8];
            o0A = mfma16(vf0, pfA, o0A);
            o1A = mfma16(vf1, pfA, o1A);
            o0B = mfma16(vf0, pfB, o0B);
            o1B = mfma16(vf1, pfB, o1B);
            laccA = mfma16(ones, pfA, laccA);
            laccB = mfma16(ones, pfB, laccB);
        }
    }
    size_t rowA = rb + q0 + ql, rowB = rowA + 16;
    float* obA = Op + (size_t)sp * mrows * 256 + rowA * 256 + h * 32;
    float* obB = Op + (size_t)sp * mrows * 256 + rowB * 256 + h * 32;
    *(f32x4*)&obA[gq * 4]      = o0A;
    *(f32x4*)&obA[16 + gq * 4] = o1A;
    *(f32x4*)&obB[gq * 4]      = o0B;
    *(f32x4*)&obB[16 + gq * 4] = o1B;
    if (gq == 0) {
        Lp[(size_t)sp * mrows * 8 + rowA * 8 + h] = laccA[0];
        Lp[(size_t)sp * mrows * 8 + rowB * 8 + h] = laccB[0];
    }
}

// combine: Out = bf16( sum_sp Op / sum_sp Lp ). 8 rows/block.
template<int SPLIT>
__global__ __launch_bounds__(256) void combine(const float* __restrict__ Op,
                                               const float* __restrict__ Lp,
                                               ushort_t* __restrict__ Out,
                                               int mrows) {
    int t = threadIdx.x;
    size_t r = (size_t)blockIdx.x * 8 + (t >> 5);
    int c0 = (t & 31) * 8, h = c0 >> 5;
    float l = 0.f;
    f32x4 a = {0.f, 0.f, 0.f, 0.f}, b = a;
#pragma unroll
    for (int sp = 0; sp < SPLIT; sp++) {
        l += Lp[(size_t)sp * mrows * 8 + r * 8 + h];
        a += *(const f32x4*)&Op[(size_t)sp * mrows * 256 + r * 256 + c0];
        b += *(const f32x4*)&Op[(size_t)sp * mrows * 256 + r * 256 + c0 + 4];
    }
    float inv = 1.f / l;
    u32x4 o = {cvtpk(a.x * inv, a.y * inv), cvtpk(a.z * inv, a.w * inv),
               cvtpk(b.x * inv, b.y * inv), cvtpk(b.z * inv, b.w * inv)};
    *(u32x4*)&Out[r * 256 + c0] = o;
}

// ---------------------------------------------------------------------------
extern "C" void kernel_launch(void* const* d_in, const int* in_sizes, int n_in,
                              void* d_out, int out_size, void* d_ws, size_t ws_size,
                              hipStream_t stream) {
    const float* f0_in = (const float*)d_in[0];
    const float* f1_in = (const float*)d_in[1];
    const float* Wq = (const float*)d_in[2];
    const float* Wk = (const float*)d_in[3];
    const float* Wv = (const float*)d_in[4];
    const float* Wo = (const float*)d_in[5];

    float* F0 = (float*)d_out;
    float* F1 = F0 + MMDD;

    ushort_t* Fb  = (ushort_t*)d_ws;              // 4 MB bf16 [f0;f1]
    ushort_t* Qb  = Fb  + 2 * MMDD;               // 4 MB
    ushort_t* Kb  = Qb  + 2 * MMDD;               // 4 MB (K, then combined T)
    ushort_t* Vtb = Kb  + 2 * MMDD;               // 4 MB
    ushort_t* Wb  = Vtb + 2 * MMDD;               // 4 MB bf16 weights
    float*    Opw = (float*)(Wb + 2 * MMDD);      // 16 MB partial O
    float*    Lpw = Opw + (size_t)4 * 1048576;    // 0.5 MB partial l
    float*    tab = Lpw + 131072;                 // 2 MB rope table
    ushort_t* Tt  = (ushort_t*)Opw;               // bf16 temp (pre-rope), aliases Opw

    ushort_t* Wqb = Wb;
    ushort_t* Wkb = Wb + (size_t)NLAYERS * 65536;
    ushort_t* Wvb = Wb + (size_t)2 * NLAYERS * 65536;
    ushort_t* Wob = Wb + (size_t)3 * NLAYERS * 65536;

    const size_t fbytes = MMDD * sizeof(float);
    hipMemcpyAsync(F0, f0_in, fbytes, hipMemcpyDeviceToDevice, stream);
    hipMemcpyAsync(F1, f1_in, fbytes, hipMemcpyDeviceToDevice, stream);
    convbf<<<1024, 256, 0, stream>>>(F0, Fb, 262144);
    convbf<<<256, 256, 0, stream>>>(Wq, Wqb, 65536);
    convbf<<<256, 256, 0, stream>>>(Wk, Wkb, 65536);
    convbf<<<256, 256, 0, stream>>>(Wv, Wvb, 65536);
    convbf<<<256, 256, 0, stream>>>(Wo, Wob, 65536);
    rtab<<<LL, 128, 0, stream>>>(tab);

    for (int i = 0; i < NLAYERS; i++) {
        const ushort_t* wq = Wqb + (size_t)i * 65536;
        const ushort_t* wk = Wkb + (size_t)i * 65536;
        const ushort_t* wv = Wvb + (size_t)i * 65536;
        const ushort_t* wo = Wob + (size_t)i * 65536;

        if ((i & 1) == 0) {
            // self: both streams batched (M=8192), SPLIT=2
            gemm_b<2, 128><<<512, 256, 0, stream>>>(Fb, wq, nullptr, nullptr, Tt);
            rope3<1><<<1024, 256, 0, stream>>>(Tt, Qb, tab);     // Q * CSC
            gemm_b<2, 128><<<512, 256, 0, stream>>>(Fb, wk, nullptr, nullptr, Tt);
            rope3<0><<<1024, 256, 0, stream>>>(Tt, Kb, tab);
            gemm_b<3, 128><<<512, 256, 0, stream>>>(Fb, wv, nullptr, nullptr, Vtb);
            attn4<2><<<1024, 256, 0, stream>>>(Qb, Kb, Vtb, Opw, Lpw, MM * 2);
            combine<2><<<1024, 256, 0, stream>>>(Opw, Lpw, Kb, MM * 2);
            gemm_b<1, 128><<<512, 256, 0, stream>>>(Kb, wo, F0, F0, Fb);
        } else {
            // cross: Q for BOTH streams (pre-update), then sequential passes
            gemm_b<4, 128><<<512, 256, 0, stream>>>(Fb, wq, nullptr, nullptr, Qb);
            for (int s = 0; s < 2; s++) {
                const ushort_t* sb = Fb + (size_t)(1 - s) * MMDD;
                float* xf = s ? F1 : F0;
                ushort_t* xbw = Fb + (size_t)s * MMDD;
                gemm_b<2, 64><<<256, 256, 0, stream>>>(sb, wk, nullptr, nullptr, Kb);
                gemm_b<3, 64><<<256, 256, 0, stream>>>(sb, wv, nullptr, nullptr, Vtb);
                attn4<4><<<1024, 256, 0, stream>>>(Qb + (size_t)s * MMDD,
                                                   Kb, Vtb, Opw, Lpw, MM);
                combine<4><<<512, 256, 0, stream>>>(Opw, Lpw, Kb, MM);
                gemm_b<1, 64><<<256, 256, 0, stream>>>(Kb, wo, xf, xf, xbw);
            }
        }
    }
}

// Round 6
// 616.962 us; speedup vs baseline: 51.2808x; 1.0537x over previous
//
#include <hip/hip_runtime.h>

#define BB   2
#define LL   2048
#define DD   256
#define NH   8
#define MM   (BB*LL)
#define NLAYERS 8
#define MMDD ((size_t)MM*DD)

typedef unsigned short ushort_t;
typedef __attribute__((ext_vector_type(8))) short  short8;
typedef __attribute__((ext_vector_type(4))) float  f32x4;
typedef __attribute__((ext_vector_type(4))) unsigned int u32x4;
typedef __attribute__((ext_vector_type(2))) unsigned int u32x2;

#define CSC 0.2550500394f   /* 32^-0.5 * log2(e), folded into Q */

#define WAITV2 asm volatile("s_waitcnt vmcnt(2)" ::: "memory")
#define WAITV4 asm volatile("s_waitcnt vmcnt(4)" ::: "memory")
#define WAITV0 asm volatile("s_waitcnt vmcnt(0)" ::: "memory")
#define BAR()  __builtin_amdgcn_s_barrier()
#define SCHED0 __builtin_amdgcn_sched_barrier(0)

__device__ __forceinline__ f32x4 mfma16(short8 a, short8 b, f32x4 c) {
    return __builtin_amdgcn_mfma_f32_16x16x32_bf16(a, b, c, 0, 0, 0);
}
__device__ __forceinline__ unsigned cvtpk(float lo, float hi) {
    unsigned r;
    asm volatile("v_cvt_pk_bf16_f32 %0, %1, %2" : "=v"(r) : "v"(lo), "v"(hi));
    return r;
}
__device__ __forceinline__ float bf2f(unsigned short h) {
    return __builtin_bit_cast(float, ((unsigned)h) << 16);
}
__device__ __forceinline__ void gll16(const void* gsrc, void* ldst) {
    __builtin_amdgcn_global_load_lds(
        (const __attribute__((address_space(1))) unsigned int*)gsrc,
        (__attribute__((address_space(3))) unsigned int*)ldst, 16, 0, 0);
}

// ---------------------------------------------------------------------------
__global__ __launch_bounds__(256) void convbf(const float* __restrict__ in,
                                              ushort_t* __restrict__ out, int n8) {
    int i = blockIdx.x * 256 + threadIdx.x;
    if (i >= n8) return;
    const f32x4* p = (const f32x4*)(in + (size_t)i * 8);
    f32x4 a = p[0], b = p[1];
    u32x4 o = {cvtpk(a.x, a.y), cvtpk(a.z, a.w), cvtpk(b.x, b.y), cvtpk(b.z, b.w)};
    *(u32x4*)&out[(size_t)i * 8] = o;
}

// all 4 weight tensors -> bf16 in one launch (1024 blocks)
__global__ __launch_bounds__(256) void wconv(const float* __restrict__ a,
                                             const float* __restrict__ b,
                                             const float* __restrict__ c,
                                             const float* __restrict__ d,
                                             ushort_t* __restrict__ out) {
    int i = blockIdx.x * 256 + threadIdx.x;        // 0..262143
    int reg = i >> 16, loc = i & 65535;
    const float* src = reg == 0 ? a : reg == 1 ? b : reg == 2 ? c : d;
    const f32x4* p = (const f32x4*)(src + (size_t)loc * 8);
    f32x4 x = p[0], y = p[1];
    u32x4 o = {cvtpk(x.x, x.y), cvtpk(x.z, x.w), cvtpk(y.x, y.y), cvtpk(y.z, y.w)};
    *(u32x4*)&out[(size_t)reg * 524288 + (size_t)loc * 8] = o;
}

__global__ __launch_bounds__(128) void rtab(float* __restrict__ tab) {
    int p = blockIdx.x, j = threadIdx.x;
    float inv = __expf(-((float)j / 128.f) * 9.210340371976184f);
    float s, c;
    sincosf((float)p * inv, &s, &c);
    tab[(size_t)p * 256 + j]       = c;
    tab[(size_t)p * 256 + 128 + j] = s;
}

// RoPE for Q and K in one launch: grid.y=0 -> Q (xCSC), 1 -> K. 8 rows/block.
__global__ __launch_bounds__(256) void rope_qk(const ushort_t* __restrict__ SQ,
                                               const ushort_t* __restrict__ SK,
                                               ushort_t* __restrict__ DQ,
                                               ushort_t* __restrict__ DK,
                                               const float* __restrict__ tab) {
    const bool isq = (blockIdx.y == 0);
    const ushort_t* S = isq ? SQ : SK;
    ushort_t* D = isq ? DQ : DK;
    int t = threadIdx.x;
    int row = blockIdx.x * 8 + (t >> 5);
    int jj = (t & 31) * 4;
    int pos = row & (LL - 1);
    u32x2 va = *(const u32x2*)&S[(size_t)row * 256 + jj];
    u32x2 vb = *(const u32x2*)&S[(size_t)row * 256 + 128 + jj];
    f32x4 a = {bf2f(va.x & 0xffff), bf2f(va.x >> 16),
               bf2f(va.y & 0xffff), bf2f(va.y >> 16)};
    f32x4 b = {bf2f(vb.x & 0xffff), bf2f(vb.x >> 16),
               bf2f(vb.y & 0xffff), bf2f(vb.y >> 16)};
    f32x4 c = *(const f32x4*)&tab[(size_t)pos * 256 + jj];
    f32x4 s = *(const f32x4*)&tab[(size_t)pos * 256 + 128 + jj];
    f32x4 o1 = a * c - b * s;
    f32x4 o2 = b * c + a * s;
    if (isq) { o1 *= CSC; o2 *= CSC; }
    u32x2 p1 = {cvtpk(o1.x, o1.y), cvtpk(o1.z, o1.w)};
    u32x2 p2 = {cvtpk(o2.x, o2.y), cvtpk(o2.z, o2.w)};
    *(u32x2*)&D[(size_t)row * 256 + jj]       = p1;
    *(u32x2*)&D[(size_t)row * 256 + 128 + jj] = p2;
}

// ---------------------------------------------------------------------------
// Pipelined bf16 MFMA GEMM, 64x64 tile, BK=64 chunks, 3 LDS buffers, counted
// vmcnt + raw barrier. Multi-region N (fused QKV): bx<NQ -> Q region (mode
// QMODE), next NK -> K (mode 2), next NV -> V^T (mode 3).
// modes: 1 fp32 residual + bf16 dual | 2 bf16 | 3 bf16 V^T | 4 bf16*CSC
// ---------------------------------------------------------------------------
template<int NQ, int NK, int NV, int QMODE, int NTY>
__global__ __launch_bounds__(256) void gemm5(const ushort_t* __restrict__ X,
                                             const ushort_t* __restrict__ WQ,
                                             const ushort_t* __restrict__ WK,
                                             const ushort_t* __restrict__ WV,
                                             ushort_t* __restrict__ DQ,
                                             ushort_t* __restrict__ DK,
                                             ushort_t* __restrict__ DVT,
                                             const float* __restrict__ Res,
                                             float* __restrict__ OutF) {
    constexpr int NTX = NQ + NK + NV;
    __shared__ ushort_t Xb[3][4096];
    __shared__ ushort_t Wb[3][4096];
    const int tid = threadIdx.x, ln = tid & 63, w = tid >> 6;
    const int f = blockIdx.x;
    const int xcd = f & 7, s = f >> 3;
    const int bx = s % NTX, byg = s / NTX;
    const int by = xcd * (NTY / 8) + byg;
    const int m0 = by * 64;

    const ushort_t* W; ushort_t* DH; int n0, mode;
    if (NQ && bx < NQ)           { W = WQ; DH = DQ;  mode = QMODE; n0 = bx * 64; }
    else if (NK && bx < NQ + NK) { W = WK; DH = DK;  mode = 2; n0 = (bx - NQ) * 64; }
    else                         { W = WV; DH = DVT; mode = 3; n0 = (bx - NQ - NK) * 64; }

    auto stage = [&](int c, int buf) {
#pragma unroll
        for (int i = 0; i < 2; i++) {
            int sl = (w * 2 + i) * 64 + ln;          // slot 0..511
            int r = sl >> 3, x = sl & 7;
            int col = c * 64 + ((x ^ (r & 7)) << 3);
            gll16(X + (size_t)(m0 + r) * 256 + col, &Xb[buf][(w * 2 + i) * 512]);
            gll16(W + (size_t)(n0 + r) * 256 + col, &Wb[buf][(w * 2 + i) * 512]);
        }
    };

    const int ql = ln & 15, gq = ln >> 4;
    const int wm = w >> 1, wn = w & 1;
    f32x4 z4 = {0.f, 0.f, 0.f, 0.f};
    f32x4 acc[2][2] = {{z4, z4}, {z4, z4}};

    stage(0, 0);
    stage(1, 1);
#pragma unroll
    for (int c = 0; c < 4; c++) {
        if (c < 3) { WAITV4; } else { WAITV0; }
        BAR(); SCHED0;
        if (c + 2 < 4) stage(c + 2, (c + 2) % 3);
        const ushort_t* XL = Xb[c % 3];
        const ushort_t* WL = Wb[c % 3];
        __builtin_amdgcn_s_setprio(1);
#pragma unroll
        for (int ks = 0; ks < 2; ks++) {
            int cc = ks * 4 + gq;
            int r0 = 32 * wm + ql, r1 = r0 + 16;
            int nr0 = 32 * wn + ql, nr1 = nr0 + 16;
            short8 a0 = *(const short8*)&XL[(r0 * 8 + (cc ^ (r0 & 7))) * 8];
            short8 a1 = *(const short8*)&XL[(r1 * 8 + (cc ^ (r1 & 7))) * 8];
            short8 b0 = *(const short8*)&WL[(nr0 * 8 + (cc ^ (nr0 & 7))) * 8];
            short8 b1 = *(const short8*)&WL[(nr1 * 8 + (cc ^ (nr1 & 7))) * 8];
            acc[0][0] = mfma16(a0, b0, acc[0][0]);
            acc[0][1] = mfma16(a0, b1, acc[0][1]);
            acc[1][0] = mfma16(a1, b0, acc[1][0]);
            acc[1][1] = mfma16(a1, b1, acc[1][1]);
        }
        __builtin_amdgcn_s_setprio(0);
    }

    if (mode == 3) {
        float* scr = (float*)&Xb[0][0];        // 64x65 f32 = 16.6 KB (fits 24 KB)
        __syncthreads();
#pragma unroll
        for (int mf = 0; mf < 2; mf++)
#pragma unroll
            for (int nf = 0; nf < 2; nf++)
#pragma unroll
                for (int r = 0; r < 4; r++) {
                    int nloc = 32 * wn + 16 * nf + ql;
                    int mloc = 32 * wm + 16 * mf + 4 * gq + r;
                    scr[nloc * 65 + mloc] = acc[mf][nf][r];
                }
        __syncthreads();
        int nloc = tid >> 2, mc = (tid & 3) * 16;
        int ng = n0 + nloc, hh = ng >> 5, dh = ng & 31;
        int mg = m0 + mc;
        int bt = mg >> 11, key = mg & 2047;
        const float* sc = &scr[nloc * 65 + mc];
        u32x4 o1 = {cvtpk(sc[0], sc[1]), cvtpk(sc[2], sc[3]),
                    cvtpk(sc[4], sc[5]), cvtpk(sc[6], sc[7])};
        u32x4 o2 = {cvtpk(sc[8], sc[9]), cvtpk(sc[10], sc[11]),
                    cvtpk(sc[12], sc[13]), cvtpk(sc[14], sc[15])};
        ushort_t* dst = &DVT[((size_t)(bt * 8 + hh) * 32 + dh) * 2048 + key];
        *(u32x4*)dst = o1;
        *(u32x4*)(dst + 8) = o2;
    } else {
#pragma unroll
        for (int mf = 0; mf < 2; mf++)
#pragma unroll
            for (int nf = 0; nf < 2; nf++)
#pragma unroll
                for (int r = 0; r < 4; r++) {
                    int mg = m0 + 32 * wm + 16 * mf + gq * 4 + r;
                    int ng = n0 + 32 * wn + 16 * nf + ql;
                    float v = acc[mf][nf][r];
                    if (mode == 1) {
                        size_t idx = (size_t)mg * 256 + ng;
                        float o = Res[idx] + v;
                        OutF[idx] = o;
                        DH[idx] = (ushort_t)cvtpk(o, o);
                    } else if (mode == 2) {
                        DH[(size_t)mg * 256 + ng] = (ushort_t)cvtpk(v, v);
                    } else {           // mode 4
                        float vs = v * CSC;
                        DH[(size_t)mg * 256 + ng] = (ushort_t)cvtpk(vs, vs);
                    }
                }
    }
}

// ---------------------------------------------------------------------------
// Flash MFMA attention v5: 32 q/wave, fixed-shift softmax, triple-buffered
// K/V with counted vmcnt + raw barrier, setprio MFMA clusters, XCD grouping.
// SPLIT=1: writes normalized bf16 Tout. SPLIT>1: fp32 partials Op/Lp.
// grid = 512 blocks (8 xcd x 16 qb x 4 (h,z,sp)-subgroups), block=256.
// ---------------------------------------------------------------------------
template<int SPLIT>
__global__ __launch_bounds__(256) void attn5(const ushort_t* __restrict__ Q,
                                             const ushort_t* __restrict__ K,
                                             const ushort_t* __restrict__ Vt,
                                             ushort_t* __restrict__ Tout,
                                             float* __restrict__ Op,
                                             float* __restrict__ Lp, int mrows) {
    constexpr int KEYS = 2048 / SPLIT;
    constexpr int NT = KEYS / 64;
    __shared__ ushort_t K_lds[3][2048];         // 64 keys x 32 dh, chunk-major
    __shared__ ushort_t V_lds[3][2048];         // 32 dh x 64 keys, swizzled
    __shared__ ushort_t P_lds[4][2][1024];      // per-wave, per-q-half

    const int tid = threadIdx.x, ln = tid & 63, w = tid >> 6;
    const int ql = ln & 15, gq = ln >> 4;
    const int f = blockIdx.x;
    const int xcd = f & 7, slot = f >> 3;
    const int qb = slot & 15, t8 = slot >> 4;   // t8 0..3
    const int g = xcd + 8 * t8;                 // group 0..31 -> (h, zs)
    const int h = g & 7, zs = g >> 3;
    const int zz = zs / SPLIT, sp = zs % SPLIT;
    const int q0 = qb * 128 + w * 32;
    const size_t rb = (size_t)zz * 2048;

    short8 qfA = *(const short8*)&Q[(rb + q0 + ql) * 256 + h * 32 + gq * 8];
    short8 qfB = *(const short8*)&Q[(rb + q0 + 16 + ql) * 256 + h * 32 + gq * 8];

    const ushort_t* kg = K + (rb + sp * KEYS + ln) * 256 + h * 32 + w * 8;
    const int ck = w * 64 + ln, vdh = ck >> 3, vsc = (ck & 7) ^ (vdh & 7);
    const ushort_t* vg = Vt + ((size_t)(zz * 8 + h) * 32 + vdh) * 2048
                            + sp * KEYS + vsc * 8;

    gll16(kg, &K_lds[0][w * 512]);
    gll16(vg, &V_lds[0][w * 512]);
    gll16(kg + (size_t)64 * 256, &K_lds[1][w * 512]);
    gll16(vg + 64,               &V_lds[1][w * 512]);

    const short os = (short)0x3F80;             // bf16 1.0
    const short8 ones = {os, os, os, os, os, os, os, os};
    f32x4 z4 = {0.f, 0.f, 0.f, 0.f};
    f32x4 o0A = z4, o1A = z4, o0B = z4, o1B = z4, laccA = z4, laccB = z4;

    int cur = 0, pre = 2;
    for (int t = 0; t < NT; t++) {
        if (t < NT - 1) { WAITV2; } else { WAITV0; }   // own tile-t loads landed
        BAR(); SCHED0;                                  // all waves' slices landed
        if (t + 2 < NT) {                               // prefetch t+2 (buf free now)
            gll16(kg + (size_t)(t + 2) * 64 * 256, &K_lds[pre][w * 512]);
            gll16(vg + (t + 2) * 64,               &V_lds[pre][w * 512]);
        }
        const ushort_t* KL = K_lds[cur];
        const ushort_t* VL = V_lds[cur];

        f32x4 stA[4], stB[4];
        __builtin_amdgcn_s_setprio(1);
#pragma unroll
        for (int j = 0; j < 4; j++) {
            short8 kf = *(const short8*)&KL[(gq * 64 + 16 * j + ql) * 8];
            stA[j] = mfma16(kf, qfA, z4);
            stB[j] = mfma16(kf, qfB, z4);
        }
        __builtin_amdgcn_s_setprio(0);
#pragma unroll
        for (int j = 0; j < 4; j++)
#pragma unroll
            for (int r = 0; r < 4; r++) {
                stA[j][r] = __builtin_amdgcn_exp2f(stA[j][r]);
                stB[j][r] = __builtin_amdgcn_exp2f(stB[j][r]);
            }
#pragma unroll
        for (int j = 0; j < 4; j++) {
            int cc = 2 * j + (gq >> 1);
            int off = (ql * 8 + (cc ^ (ql & 7))) * 8 + (gq & 1) * 4;
            u32x2 pa = {cvtpk(stA[j][0], stA[j][1]), cvtpk(stA[j][2], stA[j][3])};
            u32x2 pb = {cvtpk(stB[j][0], stB[j][1]), cvtpk(stB[j][2], stB[j][3])};
            *(u32x2*)&P_lds[w][0][off] = pa;
            *(u32x2*)&P_lds[w][1][off] = pb;
        }
        __builtin_amdgcn_s_setprio(1);
#pragma unroll
        for (int ks = 0; ks < 2; ks++) {
            int cc = 4 * ks + gq;
            int sw = cc ^ (ql & 7);
            short8 pfA = *(const short8*)&P_lds[w][0][(ql * 8 + sw) * 8];
            short8 pfB = *(const short8*)&P_lds[w][1][(ql * 8 + sw) * 8];
            short8 vf0 = *(const short8*)&VL[((ql)      * 8 + sw) * 8];
            short8 vf1 = *(const short8*)&VL[((16 + ql) * 8 + sw) * 8];
            o0A = mfma16(vf0, pfA, o0A);
            o1A = mfma16(vf1, pfA, o1A);
            o0B = mfma16(vf0, pfB, o0B);
            o1B = mfma16(vf1, pfB, o1B);
            laccA = mfma16(ones, pfA, laccA);
            laccB = mfma16(ones, pfB, laccB);
        }
        __builtin_amdgcn_s_setprio(0);
        cur = (cur == 2) ? 0 : cur + 1;
        pre = (pre == 2) ? 0 : pre + 1;
    }

    size_t rowA = rb + q0 + ql, rowB = rowA + 16;
    if constexpr (SPLIT == 1) {
        float rA = 1.f / laccA[0], rB = 1.f / laccB[0];
        u32x2 wA0 = {cvtpk(o0A.x * rA, o0A.y * rA), cvtpk(o0A.z * rA, o0A.w * rA)};
        u32x2 wA1 = {cvtpk(o1A.x * rA, o1A.y * rA), cvtpk(o1A.z * rA, o1A.w * rA)};
        u32x2 wB0 = {cvtpk(o0B.x * rB, o0B.y * rB), cvtpk(o0B.z * rB, o0B.w * rB)};
        u32x2 wB1 = {cvtpk(o1B.x * rB, o1B.y * rB), cvtpk(o1B.z * rB, o1B.w * rB)};
        *(u32x2*)&Tout[rowA * 256 + h * 32 + gq * 4]      = wA0;
        *(u32x2*)&Tout[rowA * 256 + h * 32 + 16 + gq * 4] = wA1;
        *(u32x2*)&Tout[rowB * 256 + h * 32 + gq * 4]      = wB0;
        *(u32x2*)&Tout[rowB * 256 + h * 32 + 16 + gq * 4] = wB1;
    } else {
        float* obA = Op + (size_t)sp * mrows * 256 + rowA * 256 + h * 32;
        float* obB = Op + (size_t)sp * mrows * 256 + rowB * 256 + h * 32;
        *(f32x4*)&obA[gq * 4]      = o0A;
        *(f32x4*)&obA[16 + gq * 4] = o1A;
        *(f32x4*)&obB[gq * 4]      = o0B;
        *(f32x4*)&obB[16 + gq * 4] = o1B;
        if (gq == 0) {
            Lp[(size_t)sp * mrows * 8 + rowA * 8 + h] = laccA[0];
            Lp[(size_t)sp * mrows * 8 + rowB * 8 + h] = laccB[0];
        }
    }
}

// combine: Out = bf16( sum_sp Op / sum_sp Lp ). 8 rows/block.
template<int SPLIT>
__global__ __launch_bounds__(256) void combine(const float* __restrict__ Op,
                                               const float* __restrict__ Lp,
                                               ushort_t* __restrict__ Out,
                                               int mrows) {
    int t = threadIdx.x;
    size_t r = (size_t)blockIdx.x * 8 + (t >> 5);
    int c0 = (t & 31) * 8, h = c0 >> 5;
    float l = 0.f;
    f32x4 a = {0.f, 0.f, 0.f, 0.f}, b = a;
#pragma unroll
    for (int sp = 0; sp < SPLIT; sp++) {
        l += Lp[(size_t)sp * mrows * 8 + r * 8 + h];
        a += *(const f32x4*)&Op[(size_t)sp * mrows * 256 + r * 256 + c0];
        b += *(const f32x4*)&Op[(size_t)sp * mrows * 256 + r * 256 + c0 + 4];
    }
    float inv = 1.f / l;
    u32x4 o = {cvtpk(a.x * inv, a.y * inv), cvtpk(a.z * inv, a.w * inv),
               cvtpk(b.x * inv, b.y * inv), cvtpk(b.z * inv, b.w * inv)};
    *(u32x4*)&Out[r * 256 + c0] = o;
}

// ---------------------------------------------------------------------------
extern "C" void kernel_launch(void* const* d_in, const int* in_sizes, int n_in,
                              void* d_out, int out_size, void* d_ws, size_t ws_size,
                              hipStream_t stream) {
    const float* f0_in = (const float*)d_in[0];
    const float* f1_in = (const float*)d_in[1];
    const float* Wq = (const float*)d_in[2];
    const float* Wk = (const float*)d_in[3];
    const float* Wv = (const float*)d_in[4];
    const float* Wo = (const float*)d_in[5];

    float* F0 = (float*)d_out;
    float* F1 = F0 + MMDD;

    ushort_t* Fb  = (ushort_t*)d_ws;              // bf16 [f0;f1]      4 MB
    ushort_t* Qb  = Fb  + 2 * MMDD;
    ushort_t* Kb  = Qb  + 2 * MMDD;
    ushort_t* Vtb = Kb  + 2 * MMDD;
    ushort_t* Tbb = Vtb + 2 * MMDD;               // attn out bf16
    ushort_t* TtQ = Tbb + 2 * MMDD;               // pre-rope Q
    ushort_t* TtK = TtQ + 2 * MMDD;               // pre-rope K
    ushort_t* Wb  = TtK + 2 * MMDD;               // bf16 weights 4 MB
    float*    Opw = (float*)(Wb + 2 * MMDD);      // cross partial O (8 MB)
    float*    Lpw = Opw + (size_t)2 * MM * 256;
    float*    tab = Lpw + (size_t)2 * MM * 8;

    ushort_t* Wqb = Wb;
    ushort_t* Wkb = Wb + (size_t)NLAYERS * 65536;
    ushort_t* Wvb = Wb + (size_t)2 * NLAYERS * 65536;
    ushort_t* Wob = Wb + (size_t)3 * NLAYERS * 65536;

    const size_t fbytes = MMDD * sizeof(float);
    hipMemcpyAsync(F0, f0_in, fbytes, hipMemcpyDeviceToDevice, stream);
    hipMemcpyAsync(F1, f1_in, fbytes, hipMemcpyDeviceToDevice, stream);
    convbf<<<1024, 256, 0, stream>>>(F0, Fb, 262144);
    wconv<<<1024, 256, 0, stream>>>(Wq, Wk, Wv, Wo, Wb);
    rtab<<<LL, 128, 0, stream>>>(tab);

    for (int i = 0; i < NLAYERS; i++) {
        const ushort_t* wq = Wqb + (size_t)i * 65536;
        const ushort_t* wk = Wkb + (size_t)i * 65536;
        const ushort_t* wv = Wvb + (size_t)i * 65536;
        const ushort_t* wo = Wob + (size_t)i * 65536;

        if ((i & 1) == 0) {
            // self: both streams batched (M=8192); fused QKV; SPLIT=1 attn
            gemm5<4, 4, 4, 2, 128><<<1536, 256, 0, stream>>>(
                Fb, wq, wk, wv, TtQ, TtK, Vtb, nullptr, nullptr);
            rope_qk<<<dim3(1024, 2), 256, 0, stream>>>(TtQ, TtK, Qb, Kb, tab);
            attn5<1><<<512, 256, 0, stream>>>(Qb, Kb, Vtb, Tbb, nullptr, nullptr, 0);
            gemm5<4, 0, 0, 1, 128><<<512, 256, 0, stream>>>(
                Tbb, wo, nullptr, nullptr, Fb, nullptr, nullptr, F0, F0);
        } else {
            // cross: Q for both streams (pre-update), then sequential passes
            gemm5<4, 0, 0, 4, 128><<<512, 256, 0, stream>>>(
                Fb, wq, nullptr, nullptr, Qb, nullptr, nullptr, nullptr, nullptr);
            for (int s = 0; s < 2; s++) {
                const ushort_t* sb = Fb + (size_t)(1 - s) * MMDD;
                float* xf = s ? F1 : F0;
                ushort_t* xbw = Fb + (size_t)s * MMDD;
                gemm5<0, 4, 4, 0, 64><<<512, 256, 0, stream>>>(
                    sb, nullptr, wk, wv, nullptr, Kb, Vtb, nullptr, nullptr);
                attn5<2><<<512, 256, 0, stream>>>(Qb + (size_t)s * MMDD,
                                                  Kb, Vtb, nullptr, Opw, Lpw, MM);
                combine<2><<<512, 256, 0, stream>>>(Opw, Lpw, Tbb, MM);
                gemm5<4, 0, 0, 1, 64><<<256, 256, 0, stream>>>(
                    Tbb, wo, nullptr, nullptr, xbw, nullptr, nullptr, xf, xf);
            }
        }
    }
}

// Round 7
// 566.001 us; speedup vs baseline: 55.8979x; 1.0900x over previous
//
#include <hip/hip_runtime.h>

#define BB   2
#define LL   2048
#define DD   256
#define NH   8
#define MM   (BB*LL)
#define NLAYERS 8
#define MMDD ((size_t)MM*DD)

typedef unsigned short ushort_t;
typedef __attribute__((ext_vector_type(8))) short  short8;
typedef __attribute__((ext_vector_type(4))) float  f32x4;
typedef __attribute__((ext_vector_type(4))) unsigned int u32x4;
typedef __attribute__((ext_vector_type(2))) unsigned int u32x2;

#define CSC 0.2550500394f   /* 32^-0.5 * log2(e), folded into Q */

#define WAITV2 asm volatile("s_waitcnt vmcnt(2)" ::: "memory")
#define WAITV4 asm volatile("s_waitcnt vmcnt(4)" ::: "memory")
#define WAITV0 asm volatile("s_waitcnt vmcnt(0)" ::: "memory")
#define BAR()  __builtin_amdgcn_s_barrier()
#define SCHED0 __builtin_amdgcn_sched_barrier(0)

__device__ __forceinline__ f32x4 mfma16(short8 a, short8 b, f32x4 c) {
    return __builtin_amdgcn_mfma_f32_16x16x32_bf16(a, b, c, 0, 0, 0);
}
__device__ __forceinline__ unsigned cvtpk(float lo, float hi) {
    unsigned r;
    asm volatile("v_cvt_pk_bf16_f32 %0, %1, %2" : "=v"(r) : "v"(lo), "v"(hi));
    return r;
}
__device__ __forceinline__ float bf2f(unsigned short h) {
    return __builtin_bit_cast(float, ((unsigned)h) << 16);
}
__device__ __forceinline__ void gll16(const void* gsrc, void* ldst) {
    __builtin_amdgcn_global_load_lds(
        (const __attribute__((address_space(1))) unsigned int*)gsrc,
        (__attribute__((address_space(3))) unsigned int*)ldst, 16, 0, 0);
}

// Tile-image layouts, per (zh = z*8+h), 2048 keys x 32 dh, 64-key tiles:
//   K: off = zh*65536 + t*2048 + (dh>>3)*512 + (key&63)*8 + (dh&7)
//   V: off = zh*65536 + t*2048 + dh*64 + (((key&63)>>3)^(dh&7))*8 + (key&7)

// ---------------------------------------------------------------------------
__global__ __launch_bounds__(256) void convbf(const float* __restrict__ in,
                                              ushort_t* __restrict__ out, int n8) {
    int i = blockIdx.x * 256 + threadIdx.x;
    if (i >= n8) return;
    const f32x4* p = (const f32x4*)(in + (size_t)i * 8);
    f32x4 a = p[0], b = p[1];
    u32x4 o = {cvtpk(a.x, a.y), cvtpk(a.z, a.w), cvtpk(b.x, b.y), cvtpk(b.z, b.w)};
    *(u32x4*)&out[(size_t)i * 8] = o;
}

__global__ __launch_bounds__(256) void wconv(const float* __restrict__ a,
                                             const float* __restrict__ b,
                                             const float* __restrict__ c,
                                             const float* __restrict__ d,
                                             ushort_t* __restrict__ out) {
    int i = blockIdx.x * 256 + threadIdx.x;
    int reg = i >> 16, loc = i & 65535;
    const float* src = reg == 0 ? a : reg == 1 ? b : reg == 2 ? c : d;
    const f32x4* p = (const f32x4*)(src + (size_t)loc * 8);
    f32x4 x = p[0], y = p[1];
    u32x4 o = {cvtpk(x.x, x.y), cvtpk(x.z, x.w), cvtpk(y.x, y.y), cvtpk(y.z, y.w)};
    *(u32x4*)&out[(size_t)reg * 524288 + (size_t)loc * 8] = o;
}

__global__ __launch_bounds__(128) void rtab(float* __restrict__ tab) {
    int p = blockIdx.x, j = threadIdx.x;
    float inv = __expf(-((float)j / 128.f) * 9.210340371976184f);
    float s, c;
    sincosf((float)p * inv, &s, &c);
    tab[(size_t)p * 256 + j]       = c;
    tab[(size_t)p * 256 + 128 + j] = s;
}

// RoPE: y=0 -> Q in-place [m,256] with CSC; y=1 -> K from Src[m,256] -> K tile
// image. 8 rows/block.
__global__ __launch_bounds__(256) void rope_qk(ushort_t* __restrict__ Qio,
                                               const ushort_t* __restrict__ KSrc,
                                               ushort_t* __restrict__ KT,
                                               const float* __restrict__ tab) {
    const bool isq = (blockIdx.y == 0);
    const ushort_t* S = isq ? Qio : KSrc;
    int t = threadIdx.x;
    int row = blockIdx.x * 8 + (t >> 5);
    int jj = (t & 31) * 4;
    int pos = row & (LL - 1);
    u32x2 va = *(const u32x2*)&S[(size_t)row * 256 + jj];
    u32x2 vb = *(const u32x2*)&S[(size_t)row * 256 + 128 + jj];
    f32x4 a = {bf2f(va.x & 0xffff), bf2f(va.x >> 16),
               bf2f(va.y & 0xffff), bf2f(va.y >> 16)};
    f32x4 b = {bf2f(vb.x & 0xffff), bf2f(vb.x >> 16),
               bf2f(vb.y & 0xffff), bf2f(vb.y >> 16)};
    f32x4 c = *(const f32x4*)&tab[(size_t)pos * 256 + jj];
    f32x4 s = *(const f32x4*)&tab[(size_t)pos * 256 + 128 + jj];
    f32x4 o1 = a * c - b * s;
    f32x4 o2 = b * c + a * s;
    if (isq) { o1 *= CSC; o2 *= CSC; }
    u32x2 p1 = {cvtpk(o1.x, o1.y), cvtpk(o1.z, o1.w)};
    u32x2 p2 = {cvtpk(o2.x, o2.y), cvtpk(o2.z, o2.w)};
    if (isq) {
        *(u32x2*)&Qio[(size_t)row * 256 + jj]       = p1;
        *(u32x2*)&Qio[(size_t)row * 256 + 128 + jj] = p2;
    } else {
        int z = row >> 11, key = row & 2047;
        int tt = key >> 6, kk = key & 63;
        int hA = jj >> 5, dh = jj & 31;
        int g = dh >> 3, e = dh & 7;
        size_t base = (size_t)tt * 2048 + (size_t)g * 512 + (size_t)kk * 8 + e;
        *(u32x2*)&KT[(size_t)(z * 8 + hA) * 65536 + base]     = p1;
        *(u32x2*)&KT[(size_t)(z * 8 + hA + 4) * 65536 + base] = p2;
    }
}

// ---------------------------------------------------------------------------
// Pipelined bf16 MFMA GEMM, 64x64 tile, BK=64 chunks, 3 LDS buffers.
// Fused multi-region N: bx<NQ -> Q (QMODE), next NK -> K (KMODE), next NV ->
// V tile image. modes: 1 res+dual | 2 bf16 row | 4 bf16*CSC row | 5 K tile
// ---------------------------------------------------------------------------
template<int NQ, int NK, int NV, int QMODE, int KMODE, int NTY>
__global__ __launch_bounds__(256) void gemm5(const ushort_t* __restrict__ X,
                                             const ushort_t* __restrict__ WQ,
                                             const ushort_t* __restrict__ WK,
                                             const ushort_t* __restrict__ WV,
                                             ushort_t* __restrict__ DQ,
                                             ushort_t* __restrict__ DK,
                                             ushort_t* __restrict__ DVT,
                                             const float* __restrict__ Res,
                                             float* __restrict__ OutF) {
    constexpr int NTX = NQ + NK + NV;
    __shared__ ushort_t Xb[3][4096];
    __shared__ ushort_t Wb[3][4096];
    const int tid = threadIdx.x, ln = tid & 63, w = tid >> 6;
    const int f = blockIdx.x;
    const int xcd = f & 7, s = f >> 3;
    const int bx = s % NTX, byg = s / NTX;
    const int by = xcd * (NTY / 8) + byg;
    const int m0 = by * 64;

    const ushort_t* W; ushort_t* DH; int n0, mode;
    if (NQ && bx < NQ)           { W = WQ; DH = DQ;  mode = QMODE; n0 = bx * 64; }
    else if (NK && bx < NQ + NK) { W = WK; DH = DK;  mode = KMODE; n0 = (bx - NQ) * 64; }
    else                         { W = WV; DH = DVT; mode = 3; n0 = (bx - NQ - NK) * 64; }

    auto stage = [&](int c, int buf) {
#pragma unroll
        for (int i = 0; i < 2; i++) {
            int sl = (w * 2 + i) * 64 + ln;
            int r = sl >> 3, x = sl & 7;
            int col = c * 64 + ((x ^ (r & 7)) << 3);
            gll16(X + (size_t)(m0 + r) * 256 + col, &Xb[buf][(w * 2 + i) * 512]);
            gll16(W + (size_t)(n0 + r) * 256 + col, &Wb[buf][(w * 2 + i) * 512]);
        }
    };

    const int ql = ln & 15, gq = ln >> 4;
    const int wm = w >> 1, wn = w & 1;
    f32x4 z4 = {0.f, 0.f, 0.f, 0.f};
    f32x4 acc[2][2] = {{z4, z4}, {z4, z4}};

    stage(0, 0);
    stage(1, 1);
#pragma unroll
    for (int c = 0; c < 4; c++) {
        if (c < 3) { WAITV4; } else { WAITV0; }
        BAR(); SCHED0;
        if (c + 2 < 4) stage(c + 2, (c + 2) % 3);
        const ushort_t* XL = Xb[c % 3];
        const ushort_t* WL = Wb[c % 3];
        __builtin_amdgcn_s_setprio(1);
#pragma unroll
        for (int ks = 0; ks < 2; ks++) {
            int cc = ks * 4 + gq;
            int r0 = 32 * wm + ql, r1 = r0 + 16;
            int nr0 = 32 * wn + ql, nr1 = nr0 + 16;
            short8 a0 = *(const short8*)&XL[(r0 * 8 + (cc ^ (r0 & 7))) * 8];
            short8 a1 = *(const short8*)&XL[(r1 * 8 + (cc ^ (r1 & 7))) * 8];
            short8 b0 = *(const short8*)&WL[(nr0 * 8 + (cc ^ (nr0 & 7))) * 8];
            short8 b1 = *(const short8*)&WL[(nr1 * 8 + (cc ^ (nr1 & 7))) * 8];
            acc[0][0] = mfma16(a0, b0, acc[0][0]);
            acc[0][1] = mfma16(a0, b1, acc[0][1]);
            acc[1][0] = mfma16(a1, b0, acc[1][0]);
            acc[1][1] = mfma16(a1, b1, acc[1][1]);
        }
        __builtin_amdgcn_s_setprio(0);
    }

    if (mode == 3) {
        // LDS-transpose then store the V tile image (coalesced 16B)
        float* scr = (float*)&Xb[0][0];        // 64x65 f32
        __syncthreads();
#pragma unroll
        for (int mf = 0; mf < 2; mf++)
#pragma unroll
            for (int nf = 0; nf < 2; nf++)
#pragma unroll
                for (int r = 0; r < 4; r++) {
                    int nloc = 32 * wn + 16 * nf + ql;
                    int mloc = 32 * wm + 16 * mf + 4 * gq + r;
                    scr[nloc * 65 + mloc] = acc[mf][nf][r];
                }
        __syncthreads();
        int nloc = tid >> 2, mc = (tid & 3) * 16;
        int ng = n0 + nloc, hh = ng >> 5, dh = ng & 31;
        int mg = m0 + mc;
        int z = mg >> 11, key = mg & 2047;
        int tt = key >> 6, kk = key & 63;
        int kc0 = kk >> 3;
        const float* sc = &scr[nloc * 65 + mc];
        u32x4 o1 = {cvtpk(sc[0], sc[1]), cvtpk(sc[2], sc[3]),
                    cvtpk(sc[4], sc[5]), cvtpk(sc[6], sc[7])};
        u32x4 o2 = {cvtpk(sc[8], sc[9]), cvtpk(sc[10], sc[11]),
                    cvtpk(sc[12], sc[13]), cvtpk(sc[14], sc[15])};
        ushort_t* base = &DVT[(size_t)(z * 8 + hh) * 65536 + (size_t)tt * 2048 + dh * 64];
        *(u32x4*)&base[((kc0)     ^ (dh & 7)) * 8] = o1;
        *(u32x4*)&base[((kc0 + 1) ^ (dh & 7)) * 8] = o2;
    } else {
#pragma unroll
        for (int mf = 0; mf < 2; mf++)
#pragma unroll
            for (int nf = 0; nf < 2; nf++)
#pragma unroll
                for (int r = 0; r < 4; r++) {
                    int mg = m0 + 32 * wm + 16 * mf + gq * 4 + r;
                    int ng = n0 + 32 * wn + 16 * nf + ql;
                    float v = acc[mf][nf][r];
                    if (mode == 1) {
                        size_t idx = (size_t)mg * 256 + ng;
                        float o = Res[idx] + v;
                        OutF[idx] = o;
                        DH[idx] = (ushort_t)cvtpk(o, o);
                    } else if (mode == 2) {
                        DH[(size_t)mg * 256 + ng] = (ushort_t)cvtpk(v, v);
                    } else if (mode == 5) {     // K tile image
                        int zh = (mg >> 11) * 8 + (ng >> 5);
                        size_t off = (size_t)zh * 65536
                                   + (size_t)((mg & 2047) >> 6) * 2048
                                   + (size_t)((ng & 31) >> 3) * 512
                                   + (size_t)(mg & 63) * 8 + (ng & 7);
                        DH[off] = (ushort_t)cvtpk(v, v);
                    } else {                    // mode 4
                        float vs = v * CSC;
                        DH[(size_t)mg * 256 + ng] = (ushort_t)cvtpk(vs, vs);
                    }
                }
    }
}

// ---------------------------------------------------------------------------
// Flash MFMA attention v6: 32 q/wave, fixed-shift softmax, 3-buffer counted-
// vmcnt pipeline, tile-image K/V (fully coalesced staging), XCD grouping.
// grid = 1024 blocks: f = xcd + 8*(qb + 16*gg); g = xcd*8... (h=xcd, zs=gg).
// ZN*SPLIT must be 8 (self: 4x2, cross: 2x4). Writes fp32 partials Op/Lp.
// ---------------------------------------------------------------------------
template<int SPLIT>
__global__ __launch_bounds__(256) void attn6(const ushort_t* __restrict__ Q,
                                             const ushort_t* __restrict__ K,
                                             const ushort_t* __restrict__ Vt,
                                             float* __restrict__ Op,
                                             float* __restrict__ Lp, int mrows) {
    constexpr int KEYS = 2048 / SPLIT;
    constexpr int NT = KEYS / 64;
    __shared__ ushort_t K_lds[3][2048];
    __shared__ ushort_t V_lds[3][2048];
    __shared__ ushort_t P_lds[4][2][1024];

    const int tid = threadIdx.x, ln = tid & 63, w = tid >> 6;
    const int ql = ln & 15, gq = ln >> 4;
    const int f = blockIdx.x;
    const int xcd = f & 7, slot = f >> 3;
    const int qb = slot & 15, gg = slot >> 4;   // gg 0..7
    const int h = xcd, zs = gg;                 // 8 (zz,sp) groups per h
    const int zz = zs / SPLIT, sp = zs % SPLIT;
    const int q0 = qb * 128 + w * 32;
    const size_t rb = (size_t)zz * 2048;
    const int zh = zz * 8 + h;

    short8 qfA = *(const short8*)&Q[(rb + q0 + ql) * 256 + h * 32 + gq * 8];
    short8 qfB = *(const short8*)&Q[(rb + q0 + 16 + ql) * 256 + h * 32 + gq * 8];

    const ushort_t* kt = K  + (size_t)zh * 65536 + (size_t)sp * (KEYS >> 6) * 2048 + tid * 8;
    const ushort_t* vt = Vt + (size_t)zh * 65536 + (size_t)sp * (KEYS >> 6) * 2048 + tid * 8;

    gll16(kt,        &K_lds[0][w * 512]);
    gll16(vt,        &V_lds[0][w * 512]);
    gll16(kt + 2048, &K_lds[1][w * 512]);
    gll16(vt + 2048, &V_lds[1][w * 512]);

    const short os = (short)0x3F80;             // bf16 1.0
    const short8 ones = {os, os, os, os, os, os, os, os};
    f32x4 z4 = {0.f, 0.f, 0.f, 0.f};
    f32x4 o0A = z4, o1A = z4, o0B = z4, o1B = z4, laccA = z4, laccB = z4;

    int cur = 0, pre = 2;
    for (int t = 0; t < NT; t++) {
        if (t < NT - 1) { WAITV2; } else { WAITV0; }
        BAR(); SCHED0;
        if (t + 2 < NT) {
            gll16(kt + (size_t)(t + 2) * 2048, &K_lds[pre][w * 512]);
            gll16(vt + (size_t)(t + 2) * 2048, &V_lds[pre][w * 512]);
        }
        const ushort_t* KL = K_lds[cur];
        const ushort_t* VL = V_lds[cur];

        f32x4 stA[4], stB[4];
        __builtin_amdgcn_s_setprio(1);
#pragma unroll
        for (int j = 0; j < 4; j++) {
            short8 kf = *(const short8*)&KL[(gq * 64 + 16 * j + ql) * 8];
            stA[j] = mfma16(kf, qfA, z4);
            stB[j] = mfma16(kf, qfB, z4);
        }
        __builtin_amdgcn_s_setprio(0);
#pragma unroll
        for (int j = 0; j < 4; j++)
#pragma unroll
            for (int r = 0; r < 4; r++) {
                stA[j][r] = __builtin_amdgcn_exp2f(stA[j][r]);
                stB[j][r] = __builtin_amdgcn_exp2f(stB[j][r]);
            }
#pragma unroll
        for (int j = 0; j < 4; j++) {
            int cc = 2 * j + (gq >> 1);
            int off = (ql * 8 + (cc ^ (ql & 7))) * 8 + (gq & 1) * 4;
            u32x2 pa = {cvtpk(stA[j][0], stA[j][1]), cvtpk(stA[j][2], stA[j][3])};
            u32x2 pb = {cvtpk(stB[j][0], stB[j][1]), cvtpk(stB[j][2], stB[j][3])};
            *(u32x2*)&P_lds[w][0][off] = pa;
            *(u32x2*)&P_lds[w][1][off] = pb;
        }
        __builtin_amdgcn_s_setprio(1);
#pragma unroll
        for (int ks = 0; ks < 2; ks++) {
            int cc = 4 * ks + gq;
            int sw = cc ^ (ql & 7);
            short8 pfA = *(const short8*)&P_lds[w][0][(ql * 8 + sw) * 8];
            short8 pfB = *(const short8*)&P_lds[w][1][(ql * 8 + sw) * 8];
            short8 vf0 = *(const short8*)&VL[((ql)      * 8 + sw) * 8];
            short8 vf1 = *(const short8*)&VL[((16 + ql) * 8 + sw) * 8];
            o0A = mfma16(vf0, pfA, o0A);
            o1A = mfma16(vf1, pfA, o1A);
            o0B = mfma16(vf0, pfB, o0B);
            o1B = mfma16(vf1, pfB, o1B);
            laccA = mfma16(ones, pfA, laccA);
            laccB = mfma16(ones, pfB, laccB);
        }
        __builtin_amdgcn_s_setprio(0);
        cur = (cur == 2) ? 0 : cur + 1;
        pre = (pre == 2) ? 0 : pre + 1;
    }

    size_t rowA = rb + q0 + ql, rowB = rowA + 16;
    float* obA = Op + (size_t)sp * mrows * 256 + rowA * 256 + h * 32;
    float* obB = Op + (size_t)sp * mrows * 256 + rowB * 256 + h * 32;
    *(f32x4*)&obA[gq * 4]      = o0A;
    *(f32x4*)&obA[16 + gq * 4] = o1A;
    *(f32x4*)&obB[gq * 4]      = o0B;
    *(f32x4*)&obB[16 + gq * 4] = o1B;
    if (gq == 0) {
        Lp[(size_t)sp * mrows * 8 + rowA * 8 + h] = laccA[0];
        Lp[(size_t)sp * mrows * 8 + rowB * 8 + h] = laccB[0];
    }
}

// combine: Out = bf16( sum_sp Op / sum_sp Lp ). 8 rows/block.
template<int SPLIT>
__global__ __launch_bounds__(256) void combine(const float* __restrict__ Op,
                                               const float* __restrict__ Lp,
                                               ushort_t* __restrict__ Out,
                                               int mrows) {
    int t = threadIdx.x;
    size_t r = (size_t)blockIdx.x * 8 + (t >> 5);
    int c0 = (t & 31) * 8, h = c0 >> 5;
    float l = 0.f;
    f32x4 a = {0.f, 0.f, 0.f, 0.f}, b = a;
#pragma unroll
    for (int sp = 0; sp < SPLIT; sp++) {
        l += Lp[(size_t)sp * mrows * 8 + r * 8 + h];
        a += *(const f32x4*)&Op[(size_t)sp * mrows * 256 + r * 256 + c0];
        b += *(const f32x4*)&Op[(size_t)sp * mrows * 256 + r * 256 + c0 + 4];
    }
    float inv = 1.f / l;
    u32x4 o = {cvtpk(a.x * inv, a.y * inv), cvtpk(a.z * inv, a.w * inv),
               cvtpk(b.x * inv, b.y * inv), cvtpk(b.z * inv, b.w * inv)};
    *(u32x4*)&Out[r * 256 + c0] = o;
}

// ---------------------------------------------------------------------------
extern "C" void kernel_launch(void* const* d_in, const int* in_sizes, int n_in,
                              void* d_out, int out_size, void* d_ws, size_t ws_size,
                              hipStream_t stream) {
    const float* f0_in = (const float*)d_in[0];
    const float* f1_in = (const float*)d_in[1];
    const float* Wq = (const float*)d_in[2];
    const float* Wk = (const float*)d_in[3];
    const float* Wv = (const float*)d_in[4];
    const float* Wo = (const float*)d_in[5];

    float* F0 = (float*)d_out;
    float* F1 = F0 + MMDD;

    ushort_t* Fb  = (ushort_t*)d_ws;              // bf16 [f0;f1]  4 MB
    ushort_t* Qb  = Fb  + 2 * MMDD;               // 4 MB
    ushort_t* Khb = Qb  + 2 * MMDD;               // 4 MB K tile image
    ushort_t* Vhb = Khb + 2 * MMDD;               // 4 MB V tile image
    ushort_t* Tbb = Vhb + 2 * MMDD;               // 4 MB (pre-rope K / attn out)
    ushort_t* Wb  = Tbb + 2 * MMDD;               // 4 MB bf16 weights
    float*    Opw = (float*)(Wb + 2 * MMDD);      // 16 MB partials
    float*    Lpw = Opw + (size_t)2 * 2 * MMDD;   // 1 MB
    float*    tab = Lpw + 262144;                 // 2 MB rope table

    ushort_t* Wqb = Wb;
    ushort_t* Wkb = Wb + (size_t)NLAYERS * 65536;
    ushort_t* Wvb = Wb + (size_t)2 * NLAYERS * 65536;
    ushort_t* Wob = Wb + (size_t)3 * NLAYERS * 65536;

    const size_t fbytes = MMDD * sizeof(float);
    hipMemcpyAsync(F0, f0_in, fbytes, hipMemcpyDeviceToDevice, stream);
    hipMemcpyAsync(F1, f1_in, fbytes, hipMemcpyDeviceToDevice, stream);
    convbf<<<1024, 256, 0, stream>>>(F0, Fb, 262144);
    wconv<<<1024, 256, 0, stream>>>(Wq, Wk, Wv, Wo, Wb);
    rtab<<<LL, 128, 0, stream>>>(tab);

    for (int i = 0; i < NLAYERS; i++) {
        const ushort_t* wq = Wqb + (size_t)i * 65536;
        const ushort_t* wk = Wkb + (size_t)i * 65536;
        const ushort_t* wv = Wvb + (size_t)i * 65536;
        const ushort_t* wo = Wob + (size_t)i * 65536;

        if ((i & 1) == 0) {
            // self: both streams batched (M=8192); SPLIT=2
            gemm5<4, 4, 4, 2, 2, 128><<<1536, 256, 0, stream>>>(
                Fb, wq, wk, wv, Qb, Tbb, Vhb, nullptr, nullptr);
            rope_qk<<<dim3(1024, 2), 256, 0, stream>>>(Qb, Tbb, Khb, tab);
            attn6<2><<<1024, 256, 0, stream>>>(Qb, Khb, Vhb, Opw, Lpw, MM * 2);
            combine<2><<<1024, 256, 0, stream>>>(Opw, Lpw, Tbb, MM * 2);
            gemm5<4, 0, 0, 1, 0, 128><<<512, 256, 0, stream>>>(
                Tbb, wo, nullptr, nullptr, Fb, nullptr, nullptr, F0, F0);
        } else {
            // cross: Q for both streams (pre-update), then sequential; SPLIT=4
            gemm5<4, 0, 0, 4, 0, 128><<<512, 256, 0, stream>>>(
                Fb, wq, nullptr, nullptr, Qb, nullptr, nullptr, nullptr, nullptr);
            for (int s = 0; s < 2; s++) {
                const ushort_t* sb = Fb + (size_t)(1 - s) * MMDD;
                float* xf = s ? F1 : F0;
                ushort_t* xbw = Fb + (size_t)s * MMDD;
                gemm5<0, 4, 4, 0, 5, 64><<<512, 256, 0, stream>>>(
                    sb, nullptr, wk, wv, nullptr, Khb, Vhb, nullptr, nullptr);
                attn6<4><<<1024, 256, 0, stream>>>(Qb + (size_t)s * MMDD,
                                                   Khb, Vhb, Opw, Lpw, MM);
                combine<4><<<512, 256, 0, stream>>>(Opw, Lpw, Tbb, MM);
                gemm5<4, 0, 0, 1, 0, 64><<<256, 256, 0, stream>>>(
                    Tbb, wo, nullptr, nullptr, xbw, nullptr, nullptr, xf, xf);
            }
        }
    }
}